// Round 1
// baseline (802.350 us; speedup 1.0000x reference)
//
#include <hip/hip_runtime.h>
#include <hip/hip_bf16.h>
#include <stdint.h>

#define N_NODES 8192
#define F_DIM 256
#define K_SEL 4096

typedef __attribute__((ext_vector_type(8))) short bf16x8;   // 8 bf16 in 4 VGPRs
typedef __attribute__((ext_vector_type(4))) float f32x4;

static __device__ __forceinline__ ushort f2bf(float f) {
  union { float f; uint32_t u; } c; c.f = f;
  uint32_t u = c.u;
  uint32_t r = (u + 0x7FFFu + ((u >> 16) & 1u)) >> 16;  // RNE, no NaN in data
  return (ushort)r;
}

// 1. Xk[i] = sum_f X[i,f]*kernel[f]   (fp64 accumulate)
__global__ void xk_kernel(const float* __restrict__ X, const float* __restrict__ kern,
                          float* __restrict__ Xk) {
  __shared__ double red[256];
  int row = blockIdx.x, t = threadIdx.x;
  double p = (double)X[(size_t)row * F_DIM + t] * (double)kern[t];
  red[t] = p; __syncthreads();
  for (int off = 128; off > 0; off >>= 1) {
    if (t < off) red[t] += red[t + off];
    __syncthreads();
  }
  if (t == 0) Xk[row] = (float)red[0];
}

// 2. y[i] = sum_j A[i,j]*Xk[j]   (fp64 accumulate, coalesced A read)
__global__ void gemv_kernel(const float* __restrict__ A, const float* __restrict__ Xk,
                            float* __restrict__ y) {
  __shared__ double red[256];
  int row = blockIdx.x, t = threadIdx.x;
  const float* ar = A + (size_t)row * N_NODES;
  double s = 0.0;
  for (int j = t; j < N_NODES; j += 256) s += (double)ar[j] * (double)Xk[j];
  red[t] = s; __syncthreads();
  for (int off = 128; off > 0; off >>= 1) {
    if (t < off) red[t] += red[t + off];
    __syncthreads();
  }
  if (t == 0) y[row] = (float)red[0];
}

// 3. rank each score; selected iff rank < K  (stable top-k tie-break: lower idx wins)
__global__ void rank_kernel(const float* __restrict__ y, int* __restrict__ sel) {
  __shared__ float sc[2048];
  int i = blockIdx.x * 256 + threadIdx.x;
  float si = y[i];
  int cnt = 0;
  for (int base = 0; base < N_NODES; base += 2048) {
    for (int c = threadIdx.x; c < 2048; c += 256) sc[c] = y[base + c];
    __syncthreads();
    #pragma unroll 8
    for (int jj = 0; jj < 2048; ++jj) {
      float sj = sc[jj];
      int j = base + jj;
      cnt += (sj > si) || (sj == si && j < i);
    }
    __syncthreads();
  }
  sel[i] = (cnt < K_SEL) ? 1 : 0;
}

// 4. ordered compaction -> idx[0..K-1] ascending (== sorted top-k indices)
__global__ void scan_kernel(const int* __restrict__ sel, int* __restrict__ idx) {
  __shared__ int ps[1024];
  int t = threadIdx.x;
  int base = t * 8;
  int loc[8]; int s = 0;
  #pragma unroll
  for (int k = 0; k < 8; k++) { loc[k] = sel[base + k]; s += loc[k]; }
  ps[t] = s; __syncthreads();
  for (int off = 1; off < 1024; off <<= 1) {
    int v = (t >= off) ? ps[t - off] : 0;
    __syncthreads();
    ps[t] += v;
    __syncthreads();
  }
  int pos = (t > 0) ? ps[t - 1] : 0;
  #pragma unroll
  for (int k = 0; k < 8; k++) { if (loc[k]) idx[pos++] = base + k; }
}

// 5. gather selected rows of A -> packed bf16 [K_SEL][8192]
__global__ void growbf(const float* __restrict__ A, const int* __restrict__ idx,
                       ushort* __restrict__ Ab) {
  int m = blockIdx.x;
  int src = idx[m];
  const float4* ar = (const float4*)(A + (size_t)src * N_NODES);
  ushort* dst = Ab + (size_t)m * N_NODES;
  for (int k4 = threadIdx.x; k4 < N_NODES / 4; k4 += 256) {
    float4 v = ar[k4];
    ushort4 o; o.x = f2bf(v.x); o.y = f2bf(v.y); o.z = f2bf(v.z); o.w = f2bf(v.w);
    *(ushort4*)(dst + (size_t)k4 * 4) = o;
  }
}

// 6. transpose-gather selected cols of A -> packed bf16 Bt[n][k] = A[k][idx[n]]
__global__ void tgather(const float* __restrict__ A, const int* __restrict__ idx,
                        ushort* __restrict__ Bt) {
  __shared__ ushort tile[256][66];   // [k][n], +2 pad -> conflict-free transpose read
  __shared__ int cols[64];
  int t = threadIdx.x;
  int n0 = blockIdx.x * 64;
  int k0 = blockIdx.y * 256;
  if (t < 64) cols[t] = idx[n0 + t];
  __syncthreads();
  int tn = t & 63, tk = t >> 6;
  for (int s = 0; s < 64; s++) {
    int kk = tk * 64 + s;
    float v = A[(size_t)(k0 + kk) * N_NODES + cols[tn]];
    tile[kk][tn] = f2bf(v);
  }
  __syncthreads();
  int tkk = t & 63, tn4 = t >> 6;
  for (int s2 = 0; s2 < 16; s2++) {
    int n = s2 * 4 + tn4;
    ushort* drow = Bt + (size_t)(n0 + n) * N_NODES + k0;
    #pragma unroll
    for (int kc = 0; kc < 4; kc++) {
      drow[kc * 64 + tkk] = tile[kc * 64 + tkk][n];
    }
  }
}

// 7. C[4096][4096] = Ab(M x K) * Bt(N x K)^T  -- m97-structure 128x128 tile, BK=32
#define BM 128
#define BN 128
#define BK 32

__global__ __launch_bounds__(256) void gemm_bt(const ushort* __restrict__ Ab,
                                               const ushort* __restrict__ Bt,
                                               float* __restrict__ C) {
  __shared__ __align__(16) ushort As[BM * BK];
  __shared__ __align__(16) ushort Bs[BN * BK];
  int t = threadIdx.x;
  int lane = t & 63;
  int wave = t >> 6;
  int wm = wave & 1, wn = wave >> 1;   // 2x2 wave grid, each wave 64x64 output
  int lr = lane & 15, lh = lane >> 4;
  int m0 = blockIdx.x * BM, n0 = blockIdx.y * BN;
  f32x4 acc[4][4];
  #pragma unroll
  for (int i = 0; i < 4; i++)
    #pragma unroll
    for (int j = 0; j < 4; j++) acc[i][j] = (f32x4){0.f, 0.f, 0.f, 0.f};

  const ushort* gA = Ab + (size_t)(m0 + (t >> 2)) * N_NODES + (t & 3) * 8;
  const ushort* gB = Bt + (size_t)(n0 + (t >> 2)) * N_NODES + (t & 3) * 8;
  ushort* lA = As + t * 8;   // byte offset t*16: matches wave-uniform base + lane*16
  ushort* lB = Bs + t * 8;

  for (int kt = 0; kt < N_NODES; kt += BK) {
    __builtin_amdgcn_global_load_lds((const __attribute__((address_space(1))) void*)(gA + kt),
                                     (__attribute__((address_space(3))) void*)lA, 16, 0, 0);
    __builtin_amdgcn_global_load_lds((const __attribute__((address_space(1))) void*)(gA + kt + (size_t)64 * N_NODES),
                                     (__attribute__((address_space(3))) void*)(lA + 64 * BK), 16, 0, 0);
    __builtin_amdgcn_global_load_lds((const __attribute__((address_space(1))) void*)(gB + kt),
                                     (__attribute__((address_space(3))) void*)lB, 16, 0, 0);
    __builtin_amdgcn_global_load_lds((const __attribute__((address_space(1))) void*)(gB + kt + (size_t)64 * N_NODES),
                                     (__attribute__((address_space(3))) void*)(lB + 64 * BK), 16, 0, 0);
    __syncthreads();
    bf16x8 a[4], b[4];
    #pragma unroll
    for (int m = 0; m < 4; m++)
      a[m] = *(const bf16x8*)&As[(wm * 64 + m * 16 + lr) * BK + lh * 8];
    #pragma unroll
    for (int n = 0; n < 4; n++)
      b[n] = *(const bf16x8*)&Bs[(wn * 64 + n * 16 + lr) * BK + lh * 8];
    #pragma unroll
    for (int m = 0; m < 4; m++)
      #pragma unroll
      for (int n = 0; n < 4; n++)
        acc[m][n] = __builtin_amdgcn_mfma_f32_16x16x32_bf16(a[m], b[n], acc[m][n], 0, 0, 0);
    __syncthreads();
  }
  // epilogue: C/D layout col=lane&15, row=(lane>>4)*4+r  [m89-verified]
  #pragma unroll
  for (int m = 0; m < 4; m++) {
    int row = m0 + wm * 64 + m * 16 + lh * 4;
    #pragma unroll
    for (int n = 0; n < 4; n++) {
      int col = n0 + wn * 64 + n * 16 + lr;
      float* cp = C + (size_t)row * K_SEL + col;
      #pragma unroll
      for (int r = 0; r < 4; r++) cp[(size_t)r * K_SEL] = acc[m][n][r];
    }
  }
}

// 8. X_pooled[m,f] = X[idx[m],f] * tanh(y[idx[m]])
__global__ void xpool(const float* __restrict__ X, const float* __restrict__ y,
                      const int* __restrict__ idx, float* __restrict__ out) {
  int m = blockIdx.x;
  int i = idx[m];
  float th = tanhf(y[i]);
  out[(size_t)m * F_DIM + threadIdx.x] = X[(size_t)i * F_DIM + threadIdx.x] * th;
}

extern "C" void kernel_launch(void* const* d_in, const int* in_sizes, int n_in,
                              void* d_out, int out_size, void* d_ws, size_t ws_size,
                              hipStream_t stream) {
  const float* X    = (const float*)d_in[0];
  const float* A    = (const float*)d_in[1];
  const float* kern = (const float*)d_in[2];
  float* out = (float*)d_out;
  float* Xp = out;                                 // 4096*256
  float* Ap = out + (size_t)K_SEL * F_DIM;         // 4096*4096

  char* ws = (char*)d_ws;
  float* Xk  = (float*)(ws);                       // 8192 f32
  float* yv  = (float*)(ws + 32 * 1024);           // 8192 f32
  int*   sel = (int*)  (ws + 64 * 1024);           // 8192 i32
  int*   idx = (int*)  (ws + 96 * 1024);           // 4096 i32
  ushort* Ab = (ushort*)(ws + 128 * 1024);                                   // 64 MB
  ushort* Bt = (ushort*)(ws + 128 * 1024 + (size_t)K_SEL * N_NODES * 2);     // 64 MB

  xk_kernel  <<<N_NODES, 256, 0, stream>>>(X, kern, Xk);
  gemv_kernel<<<N_NODES, 256, 0, stream>>>(A, Xk, yv);
  rank_kernel<<<N_NODES / 256, 256, 0, stream>>>(yv, sel);
  scan_kernel<<<1, 1024, 0, stream>>>(sel, idx);
  growbf     <<<K_SEL, 256, 0, stream>>>(A, idx, Ab);
  tgather    <<<dim3(K_SEL / 64, N_NODES / 256), 256, 0, stream>>>(A, idx, Bt);
  gemm_bt    <<<dim3(K_SEL / BM, K_SEL / BN), 256, 0, stream>>>(Ab, Bt, Ap);
  xpool      <<<K_SEL, 256, 0, stream>>>(X, yv, idx, Xp);
}

// Round 2
// 622.672 us; speedup vs baseline: 1.2886x; 1.2886x over previous
//
#include <hip/hip_runtime.h>
#include <hip/hip_bf16.h>
#include <stdint.h>

#define N_NODES 8192
#define F_DIM 256
#define K_SEL 4096

typedef __attribute__((ext_vector_type(8))) short bf16x8;   // 8 bf16 in 4 VGPRs
typedef __attribute__((ext_vector_type(4))) float f32x4;

static __device__ __forceinline__ ushort f2bf(float f) {
  union { float f; uint32_t u; } c; c.f = f;
  uint32_t u = c.u;
  uint32_t r = (u + 0x7FFFu + ((u >> 16) & 1u)) >> 16;  // RNE, no NaN in data
  return (ushort)r;
}

// 1. Xk[i] = sum_f X[i,f]*kernel[f]   (fp64 accumulate)
__global__ void xk_kernel(const float* __restrict__ X, const float* __restrict__ kern,
                          float* __restrict__ Xk) {
  __shared__ double red[256];
  int row = blockIdx.x, t = threadIdx.x;
  double p = (double)X[(size_t)row * F_DIM + t] * (double)kern[t];
  red[t] = p; __syncthreads();
  for (int off = 128; off > 0; off >>= 1) {
    if (t < off) red[t] += red[t + off];
    __syncthreads();
  }
  if (t == 0) Xk[row] = (float)red[0];
}

// 2. y[i] = sum_j A[i,j]*Xk[j]   (fp64 accumulate, coalesced A read)
__global__ void gemv_kernel(const float* __restrict__ A, const float* __restrict__ Xk,
                            float* __restrict__ y) {
  __shared__ double red[256];
  int row = blockIdx.x, t = threadIdx.x;
  const float* ar = A + (size_t)row * N_NODES;
  double s = 0.0;
  for (int j = t; j < N_NODES; j += 256) s += (double)ar[j] * (double)Xk[j];
  red[t] = s; __syncthreads();
  for (int off = 128; off > 0; off >>= 1) {
    if (t < off) red[t] += red[t + off];
    __syncthreads();
  }
  if (t == 0) y[row] = (float)red[0];
}

// 3. rank each score; selected iff rank < K  (stable top-k tie-break: lower idx wins)
__global__ void rank_kernel(const float* __restrict__ y, int* __restrict__ sel) {
  __shared__ float sc[2048];
  int i = blockIdx.x * 256 + threadIdx.x;
  float si = y[i];
  int cnt = 0;
  for (int base = 0; base < N_NODES; base += 2048) {
    for (int c = threadIdx.x; c < 2048; c += 256) sc[c] = y[base + c];
    __syncthreads();
    #pragma unroll 8
    for (int jj = 0; jj < 2048; ++jj) {
      float sj = sc[jj];
      int j = base + jj;
      cnt += (sj > si) || (sj == si && j < i);
    }
    __syncthreads();
  }
  sel[i] = (cnt < K_SEL) ? 1 : 0;
}

// 4. ordered compaction -> idx[0..K-1] ascending (== sorted top-k indices)
__global__ void scan_kernel(const int* __restrict__ sel, int* __restrict__ idx) {
  __shared__ int ps[1024];
  int t = threadIdx.x;
  int base = t * 8;
  int loc[8]; int s = 0;
  #pragma unroll
  for (int k = 0; k < 8; k++) { loc[k] = sel[base + k]; s += loc[k]; }
  ps[t] = s; __syncthreads();
  for (int off = 1; off < 1024; off <<= 1) {
    int v = (t >= off) ? ps[t - off] : 0;
    __syncthreads();
    ps[t] += v;
    __syncthreads();
  }
  int pos = (t > 0) ? ps[t - 1] : 0;
  #pragma unroll
  for (int k = 0; k < 8; k++) { if (loc[k]) idx[pos++] = base + k; }
}

// 5. gather selected rows of A -> packed bf16 [K_SEL][8192]
__global__ void growbf(const float* __restrict__ A, const int* __restrict__ idx,
                       ushort* __restrict__ Ab) {
  int m = blockIdx.x;
  int src = idx[m];
  const float4* ar = (const float4*)(A + (size_t)src * N_NODES);
  ushort* dst = Ab + (size_t)m * N_NODES;
  for (int k4 = threadIdx.x; k4 < N_NODES / 4; k4 += 256) {
    float4 v = ar[k4];
    ushort4 o; o.x = f2bf(v.x); o.y = f2bf(v.y); o.z = f2bf(v.z); o.w = f2bf(v.w);
    *(ushort4*)(dst + (size_t)k4 * 4) = o;
  }
}

// 6. transpose-gather selected cols of A -> packed bf16 Bt[n][k] = A[k][idx[n]]
__global__ void tgather(const float* __restrict__ A, const int* __restrict__ idx,
                        ushort* __restrict__ Bt) {
  __shared__ ushort tile[256][66];   // [k][n], +2 pad -> conflict-free transpose read
  __shared__ int cols[64];
  int t = threadIdx.x;
  int n0 = blockIdx.x * 64;
  int k0 = blockIdx.y * 256;
  if (t < 64) cols[t] = idx[n0 + t];
  __syncthreads();
  int tn = t & 63, tk = t >> 6;
  for (int s = 0; s < 64; s++) {
    int kk = tk * 64 + s;
    float v = A[(size_t)(k0 + kk) * N_NODES + cols[tn]];
    tile[kk][tn] = f2bf(v);
  }
  __syncthreads();
  int tkk = t & 63, tn4 = t >> 6;
  for (int s2 = 0; s2 < 16; s2++) {
    int n = s2 * 4 + tn4;
    ushort* drow = Bt + (size_t)(n0 + n) * N_NODES + k0;
    #pragma unroll
    for (int kc = 0; kc < 4; kc++) {
      drow[kc * 64 + tkk] = tile[kc * 64 + tkk][n];
    }
  }
}

// ============================================================================
// 7. C[4096][4096] = Ab(MxK) * Bt(NxK)^T — 256x256 tile, BK=64, 8 waves (2Mx4N),
//    4 phases/K-tile, T2 XOR-swizzled LDS, counted vmcnt(6), setprio, XCD swizzle.
//    LDS 128 KiB: A dbuf 2x[256][64]bf16, B dbuf 2x[256][64]bf16.
//    Half-tiles (16KB each, staged 1/phase, consumption-ordered):
//      alpha = A rows {0-63,128-191}   (m-half 0)  -> quads (0,*)
//      beta  = A rows {64-127,192-255} (m-half 1)  -> quads (1,*)
//      gamma = B rows {x*64+[0,32)}    (n-half 0)  -> quads (*,0)
//      delta = B rows {x*64+[32,64)}   (n-half 1)  -> quads (*,1)
//    Stage order per tile: alpha,gamma,delta,beta. vmcnt(6) every phase keeps
//    3 half-tiles in flight and retires exactly the half the phase needs.
// ============================================================================
#define NT 128   // 8192 / 64

#define GLL(g, s) __builtin_amdgcn_global_load_lds( \
    (const __attribute__((address_space(1))) void*)(g), \
    (__attribute__((address_space(3))) void*)(s), 16, 0, 0)

#define STAGE_A(H, KTN, DSTP) \
  GLL(Agl + (size_t)aGo[H][0] + (size_t)(KTN) * 64, LDS + (DSTP) * 16384 + (aLds[H][0] >> 1)); \
  GLL(Agl + (size_t)aGo[H][1] + (size_t)(KTN) * 64, LDS + (DSTP) * 16384 + (aLds[H][1] >> 1));

#define STAGE_B(H, KTN, DSTP) \
  GLL(Bgl + (size_t)bGo[H][0] + (size_t)(KTN) * 64, LDS + 32768 + (DSTP) * 16384 + (bLds[H][0] >> 1)); \
  GLL(Bgl + (size_t)bGo[H][1] + (size_t)(KTN) * 64, LDS + 32768 + (DSTP) * 16384 + (bLds[H][1] >> 1));

#define VM6 asm volatile("s_waitcnt vmcnt(6)" ::: "memory");
#define VM4 asm volatile("s_waitcnt vmcnt(4)" ::: "memory");
#define VM2 asm volatile("s_waitcnt vmcnt(2)" ::: "memory");
#define VM0 asm volatile("s_waitcnt vmcnt(0)" ::: "memory");
#define VMNONE
#define SBAR asm volatile("s_barrier" ::: "memory");

#define PHASE(MH, NH, PAB, PBB, STAGES, WAITS) { \
  STAGES \
  WAITS \
  SBAR \
  const ushort* Ab_ = (PAB) + (MH) * 4096; \
  const ushort* Bb_ = (PBB) + (NH) * 2048; \
  bf16x8 a0k0 = *(const bf16x8*)(Ab_ + aRdE[0][0]); \
  bf16x8 a1k0 = *(const bf16x8*)(Ab_ + aRdE[1][0]); \
  bf16x8 a2k0 = *(const bf16x8*)(Ab_ + aRdE[2][0]); \
  bf16x8 a3k0 = *(const bf16x8*)(Ab_ + aRdE[3][0]); \
  bf16x8 a0k1 = *(const bf16x8*)(Ab_ + aRdE[0][1]); \
  bf16x8 a1k1 = *(const bf16x8*)(Ab_ + aRdE[1][1]); \
  bf16x8 a2k1 = *(const bf16x8*)(Ab_ + aRdE[2][1]); \
  bf16x8 a3k1 = *(const bf16x8*)(Ab_ + aRdE[3][1]); \
  bf16x8 b0k0 = *(const bf16x8*)(Bb_ + bRdE[0][0]); \
  bf16x8 b1k0 = *(const bf16x8*)(Bb_ + bRdE[1][0]); \
  bf16x8 b0k1 = *(const bf16x8*)(Bb_ + bRdE[0][1]); \
  bf16x8 b1k1 = *(const bf16x8*)(Bb_ + bRdE[1][1]); \
  asm volatile("s_waitcnt lgkmcnt(0)" ::: "memory"); \
  __builtin_amdgcn_sched_barrier(0); \
  __builtin_amdgcn_s_setprio(1); \
  acc[(MH)*4+0][(NH)*2+0] = __builtin_amdgcn_mfma_f32_16x16x32_bf16(a0k0, b0k0, acc[(MH)*4+0][(NH)*2+0], 0, 0, 0); \
  acc[(MH)*4+1][(NH)*2+0] = __builtin_amdgcn_mfma_f32_16x16x32_bf16(a1k0, b0k0, acc[(MH)*4+1][(NH)*2+0], 0, 0, 0); \
  acc[(MH)*4+2][(NH)*2+0] = __builtin_amdgcn_mfma_f32_16x16x32_bf16(a2k0, b0k0, acc[(MH)*4+2][(NH)*2+0], 0, 0, 0); \
  acc[(MH)*4+3][(NH)*2+0] = __builtin_amdgcn_mfma_f32_16x16x32_bf16(a3k0, b0k0, acc[(MH)*4+3][(NH)*2+0], 0, 0, 0); \
  acc[(MH)*4+0][(NH)*2+1] = __builtin_amdgcn_mfma_f32_16x16x32_bf16(a0k0, b1k0, acc[(MH)*4+0][(NH)*2+1], 0, 0, 0); \
  acc[(MH)*4+1][(NH)*2+1] = __builtin_amdgcn_mfma_f32_16x16x32_bf16(a1k0, b1k0, acc[(MH)*4+1][(NH)*2+1], 0, 0, 0); \
  acc[(MH)*4+2][(NH)*2+1] = __builtin_amdgcn_mfma_f32_16x16x32_bf16(a2k0, b1k0, acc[(MH)*4+2][(NH)*2+1], 0, 0, 0); \
  acc[(MH)*4+3][(NH)*2+1] = __builtin_amdgcn_mfma_f32_16x16x32_bf16(a3k0, b1k0, acc[(MH)*4+3][(NH)*2+1], 0, 0, 0); \
  acc[(MH)*4+0][(NH)*2+0] = __builtin_amdgcn_mfma_f32_16x16x32_bf16(a0k1, b0k1, acc[(MH)*4+0][(NH)*2+0], 0, 0, 0); \
  acc[(MH)*4+1][(NH)*2+0] = __builtin_amdgcn_mfma_f32_16x16x32_bf16(a1k1, b0k1, acc[(MH)*4+1][(NH)*2+0], 0, 0, 0); \
  acc[(MH)*4+2][(NH)*2+0] = __builtin_amdgcn_mfma_f32_16x16x32_bf16(a2k1, b0k1, acc[(MH)*4+2][(NH)*2+0], 0, 0, 0); \
  acc[(MH)*4+3][(NH)*2+0] = __builtin_amdgcn_mfma_f32_16x16x32_bf16(a3k1, b0k1, acc[(MH)*4+3][(NH)*2+0], 0, 0, 0); \
  acc[(MH)*4+0][(NH)*2+1] = __builtin_amdgcn_mfma_f32_16x16x32_bf16(a0k1, b1k1, acc[(MH)*4+0][(NH)*2+1], 0, 0, 0); \
  acc[(MH)*4+1][(NH)*2+1] = __builtin_amdgcn_mfma_f32_16x16x32_bf16(a1k1, b1k1, acc[(MH)*4+1][(NH)*2+1], 0, 0, 0); \
  acc[(MH)*4+2][(NH)*2+1] = __builtin_amdgcn_mfma_f32_16x16x32_bf16(a2k1, b1k1, acc[(MH)*4+2][(NH)*2+1], 0, 0, 0); \
  acc[(MH)*4+3][(NH)*2+1] = __builtin_amdgcn_mfma_f32_16x16x32_bf16(a3k1, b1k1, acc[(MH)*4+3][(NH)*2+1], 0, 0, 0); \
  __builtin_amdgcn_s_setprio(0); \
  SBAR \
}

__global__ __launch_bounds__(512, 2) void gemm256(const ushort* __restrict__ Abm,
                                                  const ushort* __restrict__ Btm,
                                                  float* __restrict__ C) {
  __shared__ ushort LDS[65536];   // 128 KiB: A[2][256][64] | B[2][256][64]
  const int t = threadIdx.x, w = t >> 6, l = t & 63;
  const int lr = l & 15, lh = l >> 4;
  const int wm = w >> 2, wn = w & 3;   // 2M x 4N wave grid, per-wave out 128x64

  // T1: bijective XCD swizzle (256 blocks, 8 XCDs, 32 blocks/XCD = 2 tile-rows)
  int orig = blockIdx.x;
  int wg = (orig & 7) * 32 + (orig >> 3);
  int bm = wg >> 4, bn = wg & 15;
  const size_t m0 = (size_t)bm * 256, n0 = (size_t)bn * 256;
  const ushort* Agl = Abm + m0 * N_NODES;
  const ushort* Bgl = Btm + n0 * N_NODES;

  // staging precompute: i = w*2+j, LDS dest linear, global source inverse-swizzled
  int aLds[2][2], aGo[2][2], bLds[2][2], bGo[2][2];
  #pragma unroll
  for (int h = 0; h < 2; ++h) {
    #pragma unroll
    for (int j = 0; j < 2; ++j) {
      int i  = w * 2 + j;
      int la = ((i < 8) ? 0 : 16384) + h * 8192 + (i & 7) * 1024 + l * 16;
      int ra = la >> 7, sa = (la >> 4) & 7;
      aLds[h][j] = la;
      aGo[h][j]  = ra * N_NODES + ((sa ^ (ra & 7)) * 8);
      int lb = (i >> 2) * 8192 + h * 4096 + (i & 3) * 1024 + l * 16;
      int rb2 = lb >> 7, sb = (lb >> 4) & 7;
      bLds[h][j] = lb;
      bGo[h][j]  = rb2 * N_NODES + ((sb ^ (rb2 & 7)) * 8);
    }
  }

  // ds_read fragment offsets (element units), swizzled: slot = o ^ (row&7)
  int aRdE[4][2], bRdE[2][2];
  #pragma unroll
  for (int mf = 0; mf < 4; ++mf)
    #pragma unroll
    for (int kk = 0; kk < 2; ++kk) {
      int row = wm * 128 + mf * 16 + lr, o = kk * 4 + lh;
      aRdE[mf][kk] = row * 64 + ((o ^ (row & 7)) * 8);
    }
  #pragma unroll
  for (int nf = 0; nf < 2; ++nf)
    #pragma unroll
    for (int kk = 0; kk < 2; ++kk) {
      int row = wn * 64 + nf * 16 + lr, o = kk * 4 + lh;
      bRdE[nf][kk] = row * 64 + ((o ^ (row & 7)) * 8);
    }

  f32x4 acc[8][4];
  #pragma unroll
  for (int i = 0; i < 8; ++i)
    #pragma unroll
    for (int j = 0; j < 4; ++j) acc[i][j] = (f32x4){0.f, 0.f, 0.f, 0.f};

  // prologue: stage all 4 half-tiles of tile 0 into buf0, drain, barrier
  STAGE_A(0, 0, 0) STAGE_B(0, 0, 0) STAGE_B(1, 0, 0) STAGE_A(1, 0, 0)
  VM0
  SBAR

  for (int kt = 0; kt < NT - 1; ++kt) {
    int p = kt & 1, pn = p ^ 1;
    const ushort* PA  = LDS + p * 16384;
    const ushort* PBX = LDS + 32768 + p * 16384;
    PHASE(0, 0, PA, PBX, STAGE_A(0, kt + 1, pn), VM6)   // stage alpha(kt+1); need alpha,gamma(kt)
    PHASE(0, 1, PA, PBX, STAGE_B(0, kt + 1, pn), VM6)   // stage gamma(kt+1); need delta(kt)
    PHASE(1, 0, PA, PBX, STAGE_B(1, kt + 1, pn), VM6)   // stage delta(kt+1); need beta(kt)
    PHASE(1, 1, PA, PBX, STAGE_A(1, kt + 1, pn), VM6)   // stage beta(kt+1)
  }
  { // last tile (kt = 127, p = 1): no staging, drain incrementally
    const ushort* PA  = LDS + 16384;
    const ushort* PBX = LDS + 32768 + 16384;
    PHASE(0, 0, PA, PBX, , VM4)
    PHASE(0, 1, PA, PBX, , VM2)
    PHASE(1, 0, PA, PBX, , VM0)
    PHASE(1, 1, PA, PBX, , VMNONE)
  }

  // epilogue: C/D layout col=lane&15, row=(lane>>4)*4+r  [m89-verified]
  #pragma unroll
  for (int mf = 0; mf < 8; ++mf) {
    #pragma unroll
    for (int nf = 0; nf < 4; ++nf) {
      float* cp = C + (m0 + wm * 128 + mf * 16 + lh * 4) * K_SEL + n0 + wn * 64 + nf * 16 + lr;
      #pragma unroll
      for (int r = 0; r < 4; ++r) cp[(size_t)r * K_SEL] = acc[mf][nf][r];
    }
  }
}

// 8. X_pooled[m,f] = X[idx[m],f] * tanh(y[idx[m]])
__global__ void xpool(const float* __restrict__ X, const float* __restrict__ y,
                      const int* __restrict__ idx, float* __restrict__ out) {
  int m = blockIdx.x;
  int i = idx[m];
  float th = tanhf(y[i]);
  out[(size_t)m * F_DIM + threadIdx.x] = X[(size_t)i * F_DIM + threadIdx.x] * th;
}

extern "C" void kernel_launch(void* const* d_in, const int* in_sizes, int n_in,
                              void* d_out, int out_size, void* d_ws, size_t ws_size,
                              hipStream_t stream) {
  const float* X    = (const float*)d_in[0];
  const float* A    = (const float*)d_in[1];
  const float* kern = (const float*)d_in[2];
  float* out = (float*)d_out;
  float* Xp = out;                                 // 4096*256
  float* Ap = out + (size_t)K_SEL * F_DIM;         // 4096*4096

  char* ws = (char*)d_ws;
  float* Xk  = (float*)(ws);                       // 8192 f32
  float* yv  = (float*)(ws + 32 * 1024);           // 8192 f32
  int*   sel = (int*)  (ws + 64 * 1024);           // 8192 i32
  int*   idx = (int*)  (ws + 96 * 1024);           // 4096 i32
  ushort* Ab = (ushort*)(ws + 128 * 1024);                                   // 64 MB
  ushort* Bt = (ushort*)(ws + 128 * 1024 + (size_t)K_SEL * N_NODES * 2);     // 64 MB

  xk_kernel  <<<N_NODES, 256, 0, stream>>>(X, kern, Xk);
  gemv_kernel<<<N_NODES, 256, 0, stream>>>(A, Xk, yv);
  rank_kernel<<<N_NODES / 256, 256, 0, stream>>>(yv, sel);
  scan_kernel<<<1, 1024, 0, stream>>>(sel, idx);
  growbf     <<<K_SEL, 256, 0, stream>>>(A, idx, Ab);
  tgather    <<<dim3(K_SEL / 64, N_NODES / 256), 256, 0, stream>>>(A, idx, Bt);
  gemm256    <<<256, 512, 0, stream>>>(Ab, Bt, Ap);
  xpool      <<<K_SEL, 256, 0, stream>>>(X, yv, idx, Xp);
}

// Round 3
// 573.798 us; speedup vs baseline: 1.3983x; 1.0852x over previous
//
#include <hip/hip_runtime.h>
#include <hip/hip_bf16.h>
#include <stdint.h>

#define N_NODES 8192
#define F_DIM 256
#define K_SEL 4096

typedef __attribute__((ext_vector_type(8))) short bf16x8;   // 8 bf16 in 4 VGPRs
typedef __attribute__((ext_vector_type(4))) float f32x4;

static __device__ __forceinline__ ushort f2bf(float f) {
  union { float f; uint32_t u; } c; c.f = f;
  uint32_t u = c.u;
  uint32_t r = (u + 0x7FFFu + ((u >> 16) & 1u)) >> 16;  // RNE, no NaN in data
  return (ushort)r;
}

// 1. Xk[i] = sum_f X[i,f]*kernel[f]   (fp64 accumulate)
__global__ void xk_kernel(const float* __restrict__ X, const float* __restrict__ kern,
                          float* __restrict__ Xk) {
  __shared__ double red[256];
  int row = blockIdx.x, t = threadIdx.x;
  double p = (double)X[(size_t)row * F_DIM + t] * (double)kern[t];
  red[t] = p; __syncthreads();
  for (int off = 128; off > 0; off >>= 1) {
    if (t < off) red[t] += red[t + off];
    __syncthreads();
  }
  if (t == 0) Xk[row] = (float)red[0];
}

// 2. y[i] = sum_j A[i,j]*Xk[j]   (fp64 accumulate, float4 loads)
__global__ void gemv_kernel(const float* __restrict__ A, const float* __restrict__ Xk,
                            float* __restrict__ y) {
  __shared__ double red[256];
  int row = blockIdx.x, t = threadIdx.x;
  const float4* ar = (const float4*)(A + (size_t)row * N_NODES);
  const float4* xk = (const float4*)Xk;
  double s = 0.0;
  for (int j = t; j < N_NODES / 4; j += 256) {
    float4 a = ar[j], x = xk[j];
    s += (double)a.x * x.x + (double)a.y * x.y + (double)a.z * x.z + (double)a.w * x.w;
  }
  red[t] = s; __syncthreads();
  for (int off = 128; off > 0; off >>= 1) {
    if (t < off) red[t] += red[t + off];
    __syncthreads();
  }
  if (t == 0) y[row] = (float)red[0];
}

// 3. rank each score; selected iff rank < K  (stable top-k tie-break: lower idx wins)
__global__ void rank_kernel(const float* __restrict__ y, int* __restrict__ sel) {
  __shared__ float sc[2048];
  int i = blockIdx.x * 256 + threadIdx.x;
  float si = y[i];
  int cnt = 0;
  for (int base = 0; base < N_NODES; base += 2048) {
    for (int c = threadIdx.x; c < 2048; c += 256) sc[c] = y[base + c];
    __syncthreads();
    #pragma unroll 8
    for (int jj = 0; jj < 2048; ++jj) {
      float sj = sc[jj];
      int j = base + jj;
      cnt += (sj > si) || (sj == si && j < i);
    }
    __syncthreads();
  }
  sel[i] = (cnt < K_SEL) ? 1 : 0;
}

// 4. ordered compaction -> idx[0..K-1] ascending (== sorted top-k indices)
__global__ void scan_kernel(const int* __restrict__ sel, int* __restrict__ idx) {
  __shared__ int ps[1024];
  int t = threadIdx.x;
  int base = t * 8;
  int loc[8]; int s = 0;
  #pragma unroll
  for (int k = 0; k < 8; k++) { loc[k] = sel[base + k]; s += loc[k]; }
  ps[t] = s; __syncthreads();
  for (int off = 1; off < 1024; off <<= 1) {
    int v = (t >= off) ? ps[t - off] : 0;
    __syncthreads();
    ps[t] += v;
    __syncthreads();
  }
  int pos = (t > 0) ? ps[t - 1] : 0;
  #pragma unroll
  for (int k = 0; k < 8; k++) { if (loc[k]) idx[pos++] = base + k; }
}

// 5. gather selected rows of A -> packed bf16 [K_SEL][8192]
__global__ void growbf(const float* __restrict__ A, const int* __restrict__ idx,
                       ushort* __restrict__ Ab) {
  int m = blockIdx.x;
  int src = idx[m];
  const float4* ar = (const float4*)(A + (size_t)src * N_NODES);
  ushort* dst = Ab + (size_t)m * N_NODES;
  for (int k4 = threadIdx.x; k4 < N_NODES / 4; k4 += 256) {
    float4 v = ar[k4];
    ushort4 o; o.x = f2bf(v.x); o.y = f2bf(v.y); o.z = f2bf(v.z); o.w = f2bf(v.w);
    *(ushort4*)(dst + (size_t)k4 * 4) = o;
  }
}

// 6. transpose-gather selected cols of A -> packed bf16 Bt[n][k] = A[k][idx[n]]
__global__ void tgather(const float* __restrict__ A, const int* __restrict__ idx,
                        ushort* __restrict__ Bt) {
  __shared__ ushort tile[256][66];   // [k][n], +2 pad -> conflict-free transpose read
  __shared__ int cols[64];
  int t = threadIdx.x;
  int n0 = blockIdx.x * 64;
  int k0 = blockIdx.y * 256;
  if (t < 64) cols[t] = idx[n0 + t];
  __syncthreads();
  int tn = t & 63, tk = t >> 6;
  const float* Acol = A + cols[tn];
  for (int b = 0; b < 4; ++b) {
    float v[16];
    #pragma unroll
    for (int u = 0; u < 16; ++u) {
      int kk = tk * 64 + b * 16 + u;
      v[u] = Acol[(size_t)(k0 + kk) * N_NODES];
    }
    #pragma unroll
    for (int u = 0; u < 16; ++u) tile[tk * 64 + b * 16 + u][tn] = f2bf(v[u]);
  }
  __syncthreads();
  int tkk = t & 63, tn4 = t >> 6;
  for (int s2 = 0; s2 < 16; s2++) {
    int n = s2 * 4 + tn4;
    ushort* drow = Bt + (size_t)(n0 + n) * N_NODES + k0;
    #pragma unroll
    for (int kc = 0; kc < 4; kc++) {
      drow[kc * 64 + tkk] = tile[kc * 64 + tkk][n];
    }
  }
}

// ============================================================================
// 7. C[4096][4096] = Ab(MxK) * Bt(NxK)^T — 256x256 tile, BK=64, 8 waves (2Mx4N),
//    4 phases/K-tile with FRAGMENT REGISTER REUSE (24 ds_read_b128/wave/tile):
//      P1 (0,0): read fa0(8)+fb0(4), stage A0'   P2 (1,0): read fa1(8), stage B0'
//      P3 (0,1): read fb1(4),        stage A1'   P4 (1,1): read none,   stage B1'
//    vmcnt(6) at P1..P3 retires exactly the half-tile each phase needs; P4 none.
//    T2 XOR swizzle (8-way, conflict-free), T5 setprio, T1 bijective XCD swizzle.
// ============================================================================
#define NT 128   // 8192 / 64

#define GLL(g, s) __builtin_amdgcn_global_load_lds( \
    (const __attribute__((address_space(1))) void*)(g), \
    (__attribute__((address_space(3))) void*)(s), 16, 0, 0)

// A half H stage: global offsets affine goA + H*524288 + J*65536 (elements);
// LDS dest bytes laB + H*8192 + J*1024 (within 32KB A-buf DSTP)
#define STAGE_A(H, KTN, DSTP) \
  GLL(Agl + goA + (H) * 524288 + (size_t)(KTN) * 64,          LDS + (DSTP) * 16384 + ((laB + (H) * 8192) >> 1)); \
  GLL(Agl + goA + (H) * 524288 + 65536 + (size_t)(KTN) * 64,  LDS + (DSTP) * 16384 + ((laB + (H) * 8192 + 1024) >> 1));

#define STAGE_B(H, KTN, DSTP) \
  GLL(Bgl + goB + (H) * 262144 + (size_t)(KTN) * 64,          LDS + 32768 + (DSTP) * 16384 + ((lbB + (H) * 4096) >> 1)); \
  GLL(Bgl + goB + (H) * 262144 + 65536 + (size_t)(KTN) * 64,  LDS + 32768 + (DSTP) * 16384 + ((lbB + (H) * 4096 + 1024) >> 1));

#define VM6 asm volatile("s_waitcnt vmcnt(6)" ::: "memory");
#define VM4 asm volatile("s_waitcnt vmcnt(4)" ::: "memory");
#define VM2 asm volatile("s_waitcnt vmcnt(2)" ::: "memory");
#define VM0 asm volatile("s_waitcnt vmcnt(0)" ::: "memory");
#define SBAR asm volatile("s_barrier" ::: "memory");
#define LGKM0 asm volatile("s_waitcnt lgkmcnt(0)" ::: "memory"); __builtin_amdgcn_sched_barrier(0);

#define LDA8(DST, PA_, MH) { \
  const ushort* Ab_ = (PA_) + (MH) * 4096; \
  _Pragma("unroll") \
  for (int mf = 0; mf < 4; ++mf) { \
    DST[mf * 2 + 0] = *(const bf16x8*)(Ab_ + aE0 + mf * 1024); \
    DST[mf * 2 + 1] = *(const bf16x8*)(Ab_ + aE1 + mf * 1024); } }

#define LDB4(DST, PB_, NH) { \
  const ushort* Bb_ = (PB_) + (NH) * 2048; \
  _Pragma("unroll") \
  for (int nf = 0; nf < 2; ++nf) { \
    DST[nf * 2 + 0] = *(const bf16x8*)(Bb_ + bE0 + nf * 1024); \
    DST[nf * 2 + 1] = *(const bf16x8*)(Bb_ + bE1 + nf * 1024); } }

#define QUAD(MH, NH, FA, FB) \
  __builtin_amdgcn_s_setprio(1); \
  _Pragma("unroll") \
  for (int kk = 0; kk < 2; ++kk) \
    _Pragma("unroll") \
    for (int nf = 0; nf < 2; ++nf) \
      _Pragma("unroll") \
      for (int mf = 0; mf < 4; ++mf) \
        acc[(MH) * 4 + mf][(NH) * 2 + nf] = __builtin_amdgcn_mfma_f32_16x16x32_bf16( \
            FA[mf * 2 + kk], FB[nf * 2 + kk], acc[(MH) * 4 + mf][(NH) * 2 + nf], 0, 0, 0); \
  __builtin_amdgcn_s_setprio(0);

__global__ __launch_bounds__(512, 2) void gemm256(const ushort* __restrict__ Abm,
                                                  const ushort* __restrict__ Btm,
                                                  float* __restrict__ C) {
  __shared__ ushort LDS[65536];   // 128 KiB: A dbuf 2x32KB | B dbuf 2x32KB
  const int t = threadIdx.x, w = t >> 6, l = t & 63;
  const int lr = l & 15, lh = l >> 4;
  const int wm = w >> 2, wn = w & 3;   // 2M x 4N wave grid, per-wave out 128x64

  // T1: bijective XCD swizzle (256 blocks, 8 XCDs, 32 blocks/XCD)
  int orig = blockIdx.x;
  int wg = (orig & 7) * 32 + (orig >> 3);
  int bm = wg >> 4, bn = wg & 15;
  const size_t m0 = (size_t)bm * 256, n0 = (size_t)bn * 256;
  const ushort* Agl = Abm + m0 * N_NODES;
  const ushort* Bgl = Btm + n0 * N_NODES;

  // staging bases (j/h offsets are compile-time immediates in STAGE_*)
  const int laB = ((w < 4) ? 0 : 16384) + ((2 * w) & 7) * 1024 + l * 16;   // bytes
  const int raB = laB >> 7, saB = (laB >> 4) & 7;
  const long goA = (long)raB * N_NODES + (long)((saB ^ (raB & 7)) * 8);    // elements
  const int lbB = (w >> 1) * 8192 + (w & 1) * 2048 + l * 16;               // bytes
  const int rbB = lbB >> 7, sbB = (lbB >> 4) & 7;
  const long goB = (long)rbB * N_NODES + (long)((sbB ^ (rbB & 7)) * 8);

  // ds_read fragment bases (element units); mf/nf step = 1024 elements (immediate)
  const int aR0 = wm * 128 + lr;
  const int aE0 = aR0 * 64 + ((lh ^ (lr & 7)) * 8);
  const int aE1 = aR0 * 64 + (((lh + 4) ^ (lr & 7)) * 8);
  const int bR0 = wn * 64 + lr;
  const int bE0 = bR0 * 64 + ((lh ^ (lr & 7)) * 8);
  const int bE1 = bR0 * 64 + (((lh + 4) ^ (lr & 7)) * 8);

  f32x4 acc[8][4];
  #pragma unroll
  for (int i = 0; i < 8; ++i)
    #pragma unroll
    for (int j = 0; j < 4; ++j) acc[i][j] = (f32x4){0.f, 0.f, 0.f, 0.f};

  bf16x8 fa0[8], fa1[8], fb0[4], fb1[4];

  // prologue: stage tile 0 (order A0,B0,A1,B1), drain, barrier
  STAGE_A(0, 0, 0) STAGE_B(0, 0, 0) STAGE_A(1, 0, 0) STAGE_B(1, 0, 0)
  VM0
  SBAR

  for (int kt = 0; kt < NT - 1; ++kt) {
    int p = kt & 1, pn = p ^ 1;
    const ushort* PA = LDS + p * 16384;
    const ushort* PB = LDS + 32768 + p * 16384;
    // P1: quad (0,0) — needs A0,B0 of tile kt
    STAGE_A(0, kt + 1, pn) VM6 SBAR
    LDA8(fa0, PA, 0) LDB4(fb0, PB, 0)
    LGKM0 QUAD(0, 0, fa0, fb0) SBAR
    // P2: quad (1,0) — needs A1; fb0 reused from regs
    STAGE_B(0, kt + 1, pn) VM6 SBAR
    LDA8(fa1, PA, 1)
    LGKM0 QUAD(1, 0, fa1, fb0) SBAR
    // P3: quad (0,1) — needs B1; fa0 reused
    STAGE_A(1, kt + 1, pn) VM6 SBAR
    LDB4(fb1, PB, 1)
    LGKM0 QUAD(0, 1, fa0, fb1) SBAR
    // P4: quad (1,1) — all fragments in regs
    STAGE_B(1, kt + 1, pn) SBAR
    QUAD(1, 1, fa1, fb1) SBAR
  }
  { // last tile (kt = 127, buf 1): no staging, drain incrementally
    const ushort* PA = LDS + 16384;
    const ushort* PB = LDS + 32768 + 16384;
    VM4 SBAR
    LDA8(fa0, PA, 0) LDB4(fb0, PB, 0)
    LGKM0 QUAD(0, 0, fa0, fb0) SBAR
    VM2 SBAR
    LDA8(fa1, PA, 1)
    LGKM0 QUAD(1, 0, fa1, fb0) SBAR
    VM0 SBAR
    LDB4(fb1, PB, 1)
    LGKM0 QUAD(0, 1, fa0, fb1) SBAR
    QUAD(1, 1, fa1, fb1)
  }

  // epilogue: C/D layout col=lane&15, row=(lane>>4)*4+r  [m89-verified]
  #pragma unroll
  for (int mf = 0; mf < 8; ++mf) {
    #pragma unroll
    for (int nf = 0; nf < 4; ++nf) {
      float* cp = C + (m0 + wm * 128 + mf * 16 + lh * 4) * K_SEL + n0 + wn * 64 + nf * 16 + lr;
      #pragma unroll
      for (int r = 0; r < 4; ++r) cp[(size_t)r * K_SEL] = acc[mf][nf][r];
    }
  }
}

// 8. X_pooled[m,f] = X[idx[m],f] * tanh(y[idx[m]])
__global__ void xpool(const float* __restrict__ X, const float* __restrict__ y,
                      const int* __restrict__ idx, float* __restrict__ out) {
  int m = blockIdx.x;
  int i = idx[m];
  float th = tanhf(y[i]);
  out[(size_t)m * F_DIM + threadIdx.x] = X[(size_t)i * F_DIM + threadIdx.x] * th;
}

extern "C" void kernel_launch(void* const* d_in, const int* in_sizes, int n_in,
                              void* d_out, int out_size, void* d_ws, size_t ws_size,
                              hipStream_t stream) {
  const float* X    = (const float*)d_in[0];
  const float* A    = (const float*)d_in[1];
  const float* kern = (const float*)d_in[2];
  float* out = (float*)d_out;
  float* Xp = out;                                 // 4096*256
  float* Ap = out + (size_t)K_SEL * F_DIM;         // 4096*4096

  char* ws = (char*)d_ws;
  float* Xk  = (float*)(ws);                       // 8192 f32
  float* yv  = (float*)(ws + 32 * 1024);           // 8192 f32
  int*   sel = (int*)  (ws + 64 * 1024);           // 8192 i32
  int*   idx = (int*)  (ws + 96 * 1024);           // 4096 i32
  ushort* Ab = (ushort*)(ws + 128 * 1024);                                   // 64 MB
  ushort* Bt = (ushort*)(ws + 128 * 1024 + (size_t)K_SEL * N_NODES * 2);     // 64 MB

  xk_kernel  <<<N_NODES, 256, 0, stream>>>(X, kern, Xk);
  gemv_kernel<<<N_NODES, 256, 0, stream>>>(A, Xk, yv);
  rank_kernel<<<N_NODES / 256, 256, 0, stream>>>(yv, sel);
  scan_kernel<<<1, 1024, 0, stream>>>(sel, idx);
  growbf     <<<K_SEL, 256, 0, stream>>>(A, idx, Ab);
  tgather    <<<dim3(K_SEL / 64, N_NODES / 256), 256, 0, stream>>>(A, idx, Bt);
  gemm256    <<<256, 512, 0, stream>>>(Ab, Bt, Ap);
  xpool      <<<K_SEL, 256, 0, stream>>>(X, yv, idx, Xp);
}

// Round 4
// 542.466 us; speedup vs baseline: 1.4791x; 1.0578x over previous
//
#include <hip/hip_runtime.h>
#include <hip/hip_bf16.h>
#include <stdint.h>

#define N_NODES 8192
#define F_DIM 256
#define K_SEL 4096

typedef __attribute__((ext_vector_type(8))) short bf16x8;   // 8 bf16 in 4 VGPRs
typedef __attribute__((ext_vector_type(4))) float f32x4;

static __device__ __forceinline__ ushort f2bf(float f) {
  union { float f; uint32_t u; } c; c.f = f;
  uint32_t u = c.u;
  uint32_t r = (u + 0x7FFFu + ((u >> 16) & 1u)) >> 16;  // RNE, no NaN in data
  return (ushort)r;
}

// 1. Xk[i] = sum_f X[i,f]*kernel[f]   (fp64 accumulate)
__global__ void xk_kernel(const float* __restrict__ X, const float* __restrict__ kern,
                          float* __restrict__ Xk) {
  __shared__ double red[256];
  int row = blockIdx.x, t = threadIdx.x;
  double p = (double)X[(size_t)row * F_DIM + t] * (double)kern[t];
  red[t] = p; __syncthreads();
  for (int off = 128; off > 0; off >>= 1) {
    if (t < off) red[t] += red[t + off];
    __syncthreads();
  }
  if (t == 0) Xk[row] = (float)red[0];
}

// 2. y[i] = sum_j A[i,j]*Xk[j]   (fp64 accumulate, float4 loads)
__global__ void gemv_kernel(const float* __restrict__ A, const float* __restrict__ Xk,
                            float* __restrict__ y) {
  __shared__ double red[256];
  int row = blockIdx.x, t = threadIdx.x;
  const float4* ar = (const float4*)(A + (size_t)row * N_NODES);
  const float4* xk = (const float4*)Xk;
  double s = 0.0;
  for (int j = t; j < N_NODES / 4; j += 256) {
    float4 a = ar[j], x = xk[j];
    s += (double)a.x * x.x + (double)a.y * x.y + (double)a.z * x.z + (double)a.w * x.w;
  }
  red[t] = s; __syncthreads();
  for (int off = 128; off > 0; off >>= 1) {
    if (t < off) red[t] += red[t + off];
    __syncthreads();
  }
  if (t == 0) y[row] = (float)red[0];
}

// 3. rank each score; selected iff rank < K  (stable top-k tie-break: lower idx wins)
__global__ void rank_kernel(const float* __restrict__ y, int* __restrict__ sel) {
  __shared__ float sc[2048];
  int i = blockIdx.x * 256 + threadIdx.x;
  float si = y[i];
  int cnt = 0;
  for (int base = 0; base < N_NODES; base += 2048) {
    for (int c = threadIdx.x; c < 2048; c += 256) sc[c] = y[base + c];
    __syncthreads();
    #pragma unroll 8
    for (int jj = 0; jj < 2048; ++jj) {
      float sj = sc[jj];
      int j = base + jj;
      cnt += (sj > si) || (sj == si && j < i);
    }
    __syncthreads();
  }
  sel[i] = (cnt < K_SEL) ? 1 : 0;
}

// 4. ordered compaction -> idx[0..K-1] ascending + exclusive-prefix rank[0..N]
__global__ void scan_kernel(const int* __restrict__ sel, int* __restrict__ idx,
                            int* __restrict__ rank) {
  __shared__ int ps[1024];
  int t = threadIdx.x;
  int base = t * 8;
  int loc[8]; int s = 0;
  #pragma unroll
  for (int k = 0; k < 8; k++) { loc[k] = sel[base + k]; s += loc[k]; }
  ps[t] = s; __syncthreads();
  for (int off = 1; off < 1024; off <<= 1) {
    int v = (t >= off) ? ps[t - off] : 0;
    __syncthreads();
    ps[t] += v;
    __syncthreads();
  }
  int pos = (t > 0) ? ps[t - 1] : 0;
  #pragma unroll
  for (int k = 0; k < 8; k++) {
    rank[base + k] = pos;
    if (loc[k]) { idx[pos] = base + k; pos++; }
  }
  if (t == 1023) rank[N_NODES] = ps[1023];
}

// 5. fused gather: one coalesced pass over A emits BOTH
//    Ab[rank[r]][k] = bf16(A[r][k])  for selected rows r, and
//    Bt[rank[c]][k] = bf16(A[k][c]) for selected cols c (transposed in LDS).
#define GR 128
#define GC 256
__global__ __launch_bounds__(256) void gatherAB(const float* __restrict__ A,
                                                const int* __restrict__ sel,
                                                const int* __restrict__ rank,
                                                ushort* __restrict__ Ab,
                                                ushort* __restrict__ Bt) {
  __shared__ ushort tile[GR][GC + 8];
  __shared__ short rlist[GR];
  __shared__ short clist[GC];
  int t = threadIdx.x, w = t >> 6, l = t & 63;
  int r0 = blockIdx.y * GR, c0 = blockIdx.x * GC;
  // load+convert: 16 lanes/row -> 256B contiguous per row-segment
  for (int p = 0; p < 8; ++p) {
    int r = p * 16 + (t >> 4);
    const float4* src = (const float4*)(A + (size_t)(r0 + r) * N_NODES + c0);
    #pragma unroll
    for (int j = 0; j < 4; ++j) {
      int c4 = (t & 15) + j * 16;
      float4 v = src[c4];
      ushort4 o; o.x = f2bf(v.x); o.y = f2bf(v.y); o.z = f2bf(v.z); o.w = f2bf(v.w);
      *(ushort4*)&tile[r][c4 * 4] = o;
    }
  }
  int rbase = rank[r0], cbase = rank[c0];
  if (t < GR && sel[r0 + t]) rlist[rank[r0 + t] - rbase] = (short)t;
  if (sel[c0 + t]) clist[rank[c0 + t] - cbase] = (short)t;
  int nR = rank[r0 + GR] - rbase;
  int nC = rank[c0 + GC] - cbase;
  __syncthreads();
  // Ab rows: wave-round-robin; 64 lanes x ushort4 = 512B coalesced per row
  for (int j = w; j < nR; j += 4) {
    int r = rlist[j];
    *(ushort4*)(Ab + (size_t)(rbase + j) * N_NODES + c0 + l * 4) = *(ushort4*)&tile[r][l * 4];
  }
  // Bt cols: 64 lanes x ushort2 = 256B coalesced per col
  for (int j = w; j < nC; j += 4) {
    int c = clist[j];
    ushort2 o; o.x = tile[2 * l][c]; o.y = tile[2 * l + 1][c];
    *(ushort2*)(Bt + (size_t)(cbase + j) * N_NODES + r0 + l * 2) = o;
  }
}

// ============================================================================
// 6. C[4096][4096] = Ab(MxK) * Bt(NxK)^T — 256x256 tile, BK=64, 8 waves (2Mx4N),
//    4 phases/K-tile, frag reuse (24 ds_read_b128/wave/tile), phase-top reads
//    (hidden under stage+barrier), ONE barrier/phase, VM4 (reads retire one
//    phase before their consumer), T2 XOR swizzle, T5 setprio, T1 XCD swizzle.
//    Retirement ledger (VM4 each phase): A0(kt)@kt-1P3, B0(kt)@kt-1P4,
//    A1(kt)@ktP1, B1(kt)@ktP2 — each visible exactly one phase before use.
// ============================================================================
#define NT 128   // 8192 / 64

#define GLL(g, s) __builtin_amdgcn_global_load_lds( \
    (const __attribute__((address_space(1))) void*)(g), \
    (__attribute__((address_space(3))) void*)(s), 16, 0, 0)

#define STAGE_A(H, KTN, DSTP) \
  GLL(Agl + goA + (H) * 524288 + (size_t)(KTN) * 64,          LDS + (DSTP) * 16384 + ((laB + (H) * 8192) >> 1)); \
  GLL(Agl + goA + (H) * 524288 + 65536 + (size_t)(KTN) * 64,  LDS + (DSTP) * 16384 + ((laB + (H) * 8192 + 1024) >> 1));

#define STAGE_B(H, KTN, DSTP) \
  GLL(Bgl + goB + (H) * 262144 + (size_t)(KTN) * 64,          LDS + 32768 + (DSTP) * 16384 + ((lbB + (H) * 4096) >> 1)); \
  GLL(Bgl + goB + (H) * 262144 + 65536 + (size_t)(KTN) * 64,  LDS + 32768 + (DSTP) * 16384 + ((lbB + (H) * 4096 + 1024) >> 1));

#define VM4 asm volatile("s_waitcnt vmcnt(4)" ::: "memory");
#define VM2 asm volatile("s_waitcnt vmcnt(2)" ::: "memory");
#define VM0 asm volatile("s_waitcnt vmcnt(0)" ::: "memory");
#define SBAR asm volatile("s_barrier" ::: "memory");
#define LGKM0 asm volatile("s_waitcnt lgkmcnt(0)" ::: "memory"); __builtin_amdgcn_sched_barrier(0);

#define LDA8(DST, PA_, MH) { \
  const ushort* Ab_ = (PA_) + (MH) * 4096; \
  _Pragma("unroll") \
  for (int mf = 0; mf < 4; ++mf) { \
    DST[mf * 2 + 0] = *(const bf16x8*)(Ab_ + aE0 + mf * 1024); \
    DST[mf * 2 + 1] = *(const bf16x8*)(Ab_ + aE1 + mf * 1024); } }

#define LDB4(DST, PB_, NH) { \
  const ushort* Bb_ = (PB_) + (NH) * 2048; \
  _Pragma("unroll") \
  for (int nf = 0; nf < 2; ++nf) { \
    DST[nf * 2 + 0] = *(const bf16x8*)(Bb_ + bE0 + nf * 1024); \
    DST[nf * 2 + 1] = *(const bf16x8*)(Bb_ + bE1 + nf * 1024); } }

#define QUAD(MH, NH, FA, FB) \
  __builtin_amdgcn_s_setprio(1); \
  _Pragma("unroll") \
  for (int kk = 0; kk < 2; ++kk) \
    _Pragma("unroll") \
    for (int nf = 0; nf < 2; ++nf) \
      _Pragma("unroll") \
      for (int mf = 0; mf < 4; ++mf) \
        acc[(MH) * 4 + mf][(NH) * 2 + nf] = __builtin_amdgcn_mfma_f32_16x16x32_bf16( \
            FA[mf * 2 + kk], FB[nf * 2 + kk], acc[(MH) * 4 + mf][(NH) * 2 + nf], 0, 0, 0); \
  __builtin_amdgcn_s_setprio(0);

__global__ __launch_bounds__(512, 2) void gemm256(const ushort* __restrict__ Abm,
                                                  const ushort* __restrict__ Btm,
                                                  float* __restrict__ C) {
  __shared__ ushort LDS[65536];   // 128 KiB: A dbuf 2x32KB | B dbuf 2x32KB
  const int t = threadIdx.x, w = t >> 6, l = t & 63;
  const int lr = l & 15, lh = l >> 4;
  const int wm = w >> 2, wn = w & 3;   // 2M x 4N wave grid, per-wave out 128x64

  // T1: bijective XCD swizzle (256 blocks, 8 XCDs, 32 blocks/XCD)
  int orig = blockIdx.x;
  int wg = (orig & 7) * 32 + (orig >> 3);
  int bm = wg >> 4, bn = wg & 15;
  const size_t m0 = (size_t)bm * 256, n0 = (size_t)bn * 256;
  const ushort* Agl = Abm + m0 * N_NODES;
  const ushort* Bgl = Btm + n0 * N_NODES;

  // staging bases (h/j offsets are compile-time immediates in STAGE_*)
  const int laB = ((w < 4) ? 0 : 16384) + ((2 * w) & 7) * 1024 + l * 16;   // bytes
  const int raB = laB >> 7, saB = (laB >> 4) & 7;
  const long goA = (long)raB * N_NODES + (long)((saB ^ (raB & 7)) * 8);    // elements
  const int lbB = (w >> 1) * 8192 + (w & 1) * 2048 + l * 16;               // bytes
  const int rbB = lbB >> 7, sbB = (lbB >> 4) & 7;
  const long goB = (long)rbB * N_NODES + (long)((sbB ^ (rbB & 7)) * 8);

  // ds_read fragment bases (element units); mf/nf step = 1024 elements
  const int aR0 = wm * 128 + lr;
  const int aE0 = aR0 * 64 + ((lh ^ (lr & 7)) * 8);
  const int aE1 = aR0 * 64 + (((lh + 4) ^ (lr & 7)) * 8);
  const int bR0 = wn * 64 + lr;
  const int bE0 = bR0 * 64 + ((lh ^ (lr & 7)) * 8);
  const int bE1 = bR0 * 64 + (((lh + 4) ^ (lr & 7)) * 8);

  f32x4 acc[8][4];
  #pragma unroll
  for (int i = 0; i < 8; ++i)
    #pragma unroll
    for (int j = 0; j < 4; ++j) acc[i][j] = (f32x4){0.f, 0.f, 0.f, 0.f};

  bf16x8 fa0[8], fa1[8], fb0[4], fb1[4];

  // prologue: stage tile 0 (A0,B0,A1,B1), drain, barrier
  STAGE_A(0, 0, 0) STAGE_B(0, 0, 0) STAGE_A(1, 0, 0) STAGE_B(1, 0, 0)
  VM0
  SBAR

  for (int kt = 0; kt < NT - 1; ++kt) {
    int p = kt & 1, pn = p ^ 1;
    const ushort* PA = LDS + p * 16384;
    const ushort* PB = LDS + 32768 + p * 16384;
    // P1: reads fa0,fb0 issued pre-barrier (data visible since kt-1 P3/P4)
    LDA8(fa0, PA, 0) LDB4(fb0, PB, 0)
    STAGE_A(0, kt + 1, pn) VM4 SBAR
    LGKM0 QUAD(0, 0, fa0, fb0)
    // P2: read fa1 (A1(kt) retired @ P1's VM4, visible after P1's SBAR)
    LDA8(fa1, PA, 1)
    STAGE_B(0, kt + 1, pn) VM4 SBAR
    LGKM0 QUAD(1, 0, fa1, fb0)
    // P3: read fb1 (B1(kt) retired @ P2's VM4)
    LDB4(fb1, PB, 1)
    STAGE_A(1, kt + 1, pn) VM4 SBAR
    LGKM0 QUAD(0, 1, fa0, fb1)
    // P4: no reads; all fragments in regs
    STAGE_B(1, kt + 1, pn) VM4 SBAR
    QUAD(1, 1, fa1, fb1)
  }
  { // last tile (kt = 127, buf 1): no staging, incremental drain
    const ushort* PA = LDS + 16384;
    const ushort* PB = LDS + 32768 + 16384;
    LDA8(fa0, PA, 0) LDB4(fb0, PB, 0)
    VM2 SBAR
    LGKM0 QUAD(0, 0, fa0, fb0)
    LDA8(fa1, PA, 1)
    VM0 SBAR
    LGKM0 QUAD(1, 0, fa1, fb0)
    LDB4(fb1, PB, 1)
    SBAR
    LGKM0 QUAD(0, 1, fa0, fb1)
    QUAD(1, 1, fa1, fb1)
  }

  // epilogue: C/D layout col=lane&15, row=(lane>>4)*4+r  [m89-verified]
  #pragma unroll
  for (int mf = 0; mf < 8; ++mf) {
    #pragma unroll
    for (int nf = 0; nf < 4; ++nf) {
      float* cp = C + (m0 + wm * 128 + mf * 16 + lh * 4) * K_SEL + n0 + wn * 64 + nf * 16 + lr;
      #pragma unroll
      for (int r = 0; r < 4; ++r) cp[(size_t)r * K_SEL] = acc[mf][nf][r];
    }
  }
}

// 7. X_pooled[m,f] = X[idx[m],f] * tanh(y[idx[m]])
__global__ void xpool(const float* __restrict__ X, const float* __restrict__ y,
                      const int* __restrict__ idx, float* __restrict__ out) {
  int m = blockIdx.x;
  int i = idx[m];
  float th = tanhf(y[i]);
  out[(size_t)m * F_DIM + threadIdx.x] = X[(size_t)i * F_DIM + threadIdx.x] * th;
}

extern "C" void kernel_launch(void* const* d_in, const int* in_sizes, int n_in,
                              void* d_out, int out_size, void* d_ws, size_t ws_size,
                              hipStream_t stream) {
  const float* X    = (const float*)d_in[0];
  const float* A    = (const float*)d_in[1];
  const float* kern = (const float*)d_in[2];
  float* out = (float*)d_out;
  float* Xp = out;                                 // 4096*256
  float* Ap = out + (size_t)K_SEL * F_DIM;         // 4096*4096

  char* ws = (char*)d_ws;
  float* Xk   = (float*)(ws);                      // 8192 f32
  float* yv   = (float*)(ws + 32 * 1024);          // 8192 f32
  int*   sel  = (int*)  (ws + 64 * 1024);          // 8192 i32
  int*   idx  = (int*)  (ws + 96 * 1024);          // 4096 i32
  int*   rank = (int*)  (ws + 128 * 1024);         // 8193 i32
  ushort* Ab = (ushort*)(ws + 192 * 1024);                                   // 64 MB
  ushort* Bt = (ushort*)(ws + 192 * 1024 + (size_t)K_SEL * N_NODES * 2);     // 64 MB

  xk_kernel  <<<N_NODES, 256, 0, stream>>>(X, kern, Xk);
  gemv_kernel<<<N_NODES, 256, 0, stream>>>(A, Xk, yv);
  rank_kernel<<<N_NODES / 256, 256, 0, stream>>>(yv, sel);
  scan_kernel<<<1, 1024, 0, stream>>>(sel, idx, rank);
  gatherAB   <<<dim3(N_NODES / GC, N_NODES / GR), 256, 0, stream>>>(A, sel, rank, Ab, Bt);
  gemm256    <<<256, 512, 0, stream>>>(Ab, Bt, Ap);
  xpool      <<<K_SEL, 256, 0, stream>>>(X, yv, idx, Xp);
}

// Round 5
// 380.190 us; speedup vs baseline: 2.1104x; 1.4268x over previous
//
#include <hip/hip_runtime.h>
#include <hip/hip_bf16.h>
#include <stdint.h>

#define N_NODES 8192
#define F_DIM 256
#define K_SEL 4096

typedef __attribute__((ext_vector_type(8))) short bf16x8;   // 8 bf16 in 4 VGPRs
typedef __attribute__((ext_vector_type(4))) float f32x4;

static __device__ __forceinline__ ushort f2bf(float f) {
  union { float f; uint32_t u; } c; c.f = f;
  uint32_t u = c.u;
  uint32_t r = (u + 0x7FFFu + ((u >> 16) & 1u)) >> 16;  // RNE, no NaN in data
  return (ushort)r;
}

// 1. Xk[i] = sum_f X[i,f]*kernel[f]   (fp64 accumulate)
__global__ void xk_kernel(const float* __restrict__ X, const float* __restrict__ kern,
                          float* __restrict__ Xk) {
  __shared__ double red[256];
  int row = blockIdx.x, t = threadIdx.x;
  double p = (double)X[(size_t)row * F_DIM + t] * (double)kern[t];
  red[t] = p; __syncthreads();
  for (int off = 128; off > 0; off >>= 1) {
    if (t < off) red[t] += red[t + off];
    __syncthreads();
  }
  if (t == 0) Xk[row] = (float)red[0];
}

// 2. y[i] = sum_j A[i,j]*Xk[j]   (fp64 accumulate, float4 loads)
__global__ void gemv_kernel(const float* __restrict__ A, const float* __restrict__ Xk,
                            float* __restrict__ y) {
  __shared__ double red[256];
  int row = blockIdx.x, t = threadIdx.x;
  const float4* ar = (const float4*)(A + (size_t)row * N_NODES);
  const float4* xk = (const float4*)Xk;
  double s = 0.0;
  #pragma unroll 4
  for (int j = t; j < N_NODES / 4; j += 256) {
    float4 a = ar[j], x = xk[j];
    s += (double)a.x * x.x + (double)a.y * x.y + (double)a.z * x.z + (double)a.w * x.w;
  }
  red[t] = s; __syncthreads();
  for (int off = 128; off > 0; off >>= 1) {
    if (t < off) red[t] += red[t + off];
    __syncthreads();
  }
  if (t == 0) y[row] = (float)red[0];
}

// 3. partial ranks: block (bx,by) counts, for 256 i's, scores beating i within
//    j-chunk [by*1024, by*1024+1024). partial[by][i]. 256 blocks -> full-chip.
__global__ void rank2d(const float* __restrict__ y, int* __restrict__ partial) {
  __shared__ float sc[1024];
  int i = blockIdx.x * 256 + threadIdx.x;
  float si = y[i];
  int j0 = blockIdx.y * 1024;
  for (int c = threadIdx.x; c < 1024; c += 256) sc[c] = y[j0 + c];
  __syncthreads();
  int cnt = 0;
  #pragma unroll 8
  for (int jj = 0; jj < 1024; ++jj) {
    float sj = sc[jj];
    int j = j0 + jj;
    cnt += (sj > si) || (sj == si && j < i);
  }
  partial[blockIdx.y * N_NODES + i] = cnt;
}

// 4. sum partials -> sel; ordered compaction -> idx ascending + prefix rank[0..N]
__global__ void scan_kernel(const int* __restrict__ partial, int* __restrict__ sel,
                            int* __restrict__ idx, int* __restrict__ rank) {
  __shared__ int ps[1024];
  int t = threadIdx.x;
  int base = t * 8;
  int loc[8]; int s = 0;
  #pragma unroll
  for (int k = 0; k < 8; k++) {
    int cnt = 0;
    #pragma unroll
    for (int b = 0; b < 8; b++) cnt += partial[b * N_NODES + base + k];
    loc[k] = (cnt < K_SEL) ? 1 : 0;
    s += loc[k];
  }
  ps[t] = s; __syncthreads();
  for (int off = 1; off < 1024; off <<= 1) {
    int v = (t >= off) ? ps[t - off] : 0;
    __syncthreads();
    ps[t] += v;
    __syncthreads();
  }
  int pos = (t > 0) ? ps[t - 1] : 0;
  #pragma unroll
  for (int k = 0; k < 8; k++) {
    sel[base + k] = loc[k];
    rank[base + k] = pos;
    if (loc[k]) { idx[pos] = base + k; pos++; }
  }
  if (t == 1023) rank[N_NODES] = ps[1023];
}

// 5. fused gather, occupancy-tuned: one coalesced pass over A emits BOTH
//    Ab[rank[r]][k] = bf16(A[r][k]) and Bt[rank[c]][k] = A[k][c] transposed.
//    33 KB LDS -> 4 blocks/CU (16 waves). Row stride 260 el (130 dwords).
#define GR 64
#define GC 256
#define GCP 260
__global__ __launch_bounds__(256) void gatherAB(const float* __restrict__ A,
                                                const int* __restrict__ sel,
                                                const int* __restrict__ rank,
                                                ushort* __restrict__ Ab,
                                                ushort* __restrict__ Bt) {
  __shared__ ushort tile[GR][GCP];
  __shared__ short rlist[GR];
  __shared__ short clist[GC];
  int t = threadIdx.x, w = t >> 6, l = t & 63;
  int r0 = blockIdx.y * GR, c0 = blockIdx.x * GC;
  // load+convert: 16 lanes x 16B = 256B contiguous per row-segment
  #pragma unroll
  for (int p = 0; p < 4; ++p) {
    int r = p * 16 + (t >> 4);
    const float4* src = (const float4*)(A + (size_t)(r0 + r) * N_NODES + c0);
    #pragma unroll
    for (int j = 0; j < 4; ++j) {
      int c4 = (t & 15) + j * 16;
      float4 v = src[c4];
      ushort4 o; o.x = f2bf(v.x); o.y = f2bf(v.y); o.z = f2bf(v.z); o.w = f2bf(v.w);
      *(ushort4*)&tile[r][c4 * 4] = o;
    }
  }
  int rbase = rank[r0], cbase = rank[c0];
  if (t < GR && sel[r0 + t]) rlist[rank[r0 + t] - rbase] = (short)t;
  if (sel[c0 + t]) clist[rank[c0 + t] - cbase] = (short)t;
  int nR = rank[r0 + GR] - rbase;
  int nC = rank[c0 + GC] - cbase;
  __syncthreads();
  // Ab rows: 64 lanes x ushort4 = 512B coalesced per selected row
  for (int j = w; j < nR; j += 4) {
    int r = rlist[j];
    *(ushort4*)(Ab + (size_t)(rbase + j) * N_NODES + c0 + l * 4) = *(ushort4*)&tile[r][l * 4];
  }
  // Bt cols: lane l reads tile[l][c] (bank l + c/2: ~conflict-free), 128B write
  for (int j = w; j < nC; j += 4) {
    int c = clist[j];
    Bt[(size_t)(cbase + j) * N_NODES + r0 + l] = tile[l][c];
  }
}

// ============================================================================
// 6. C[4096][4096] = Ab(MxK) * Bt(NxK)^T — 256x256 tile, BK=64, 8 waves (2Mx4N),
//    4 phases/K-tile, frag reuse (24 ds_read_b128/wave/tile), phase-top reads,
//    ONE barrier/phase, VM4, T2 XOR swizzle, T5 setprio, T1 XCD swizzle.
// ============================================================================
#define NT 128   // 8192 / 64

#define GLL(g, s) __builtin_amdgcn_global_load_lds( \
    (const __attribute__((address_space(1))) void*)(g), \
    (__attribute__((address_space(3))) void*)(s), 16, 0, 0)

#define STAGE_A(H, KTN, DSTP) \
  GLL(Agl + goA + (H) * 524288 + (size_t)(KTN) * 64,          LDS + (DSTP) * 16384 + ((laB + (H) * 8192) >> 1)); \
  GLL(Agl + goA + (H) * 524288 + 65536 + (size_t)(KTN) * 64,  LDS + (DSTP) * 16384 + ((laB + (H) * 8192 + 1024) >> 1));

#define STAGE_B(H, KTN, DSTP) \
  GLL(Bgl + goB + (H) * 262144 + (size_t)(KTN) * 64,          LDS + 32768 + (DSTP) * 16384 + ((lbB + (H) * 4096) >> 1)); \
  GLL(Bgl + goB + (H) * 262144 + 65536 + (size_t)(KTN) * 64,  LDS + 32768 + (DSTP) * 16384 + ((lbB + (H) * 4096 + 1024) >> 1));

#define VM4 asm volatile("s_waitcnt vmcnt(4)" ::: "memory");
#define VM2 asm volatile("s_waitcnt vmcnt(2)" ::: "memory");
#define VM0 asm volatile("s_waitcnt vmcnt(0)" ::: "memory");
#define SBAR asm volatile("s_barrier" ::: "memory");
#define LGKM0 asm volatile("s_waitcnt lgkmcnt(0)" ::: "memory"); __builtin_amdgcn_sched_barrier(0);

#define LDA8(DST, PA_, MH) { \
  const ushort* Ab_ = (PA_) + (MH) * 4096; \
  _Pragma("unroll") \
  for (int mf = 0; mf < 4; ++mf) { \
    DST[mf * 2 + 0] = *(const bf16x8*)(Ab_ + aE0 + mf * 1024); \
    DST[mf * 2 + 1] = *(const bf16x8*)(Ab_ + aE1 + mf * 1024); } }

#define LDB4(DST, PB_, NH) { \
  const ushort* Bb_ = (PB_) + (NH) * 2048; \
  _Pragma("unroll") \
  for (int nf = 0; nf < 2; ++nf) { \
    DST[nf * 2 + 0] = *(const bf16x8*)(Bb_ + bE0 + nf * 1024); \
    DST[nf * 2 + 1] = *(const bf16x8*)(Bb_ + bE1 + nf * 1024); } }

#define QUAD(MH, NH, FA, FB) \
  __builtin_amdgcn_s_setprio(1); \
  _Pragma("unroll") \
  for (int kk = 0; kk < 2; ++kk) \
    _Pragma("unroll") \
    for (int nf = 0; nf < 2; ++nf) \
      _Pragma("unroll") \
      for (int mf = 0; mf < 4; ++mf) \
        acc[(MH) * 4 + mf][(NH) * 2 + nf] = __builtin_amdgcn_mfma_f32_16x16x32_bf16( \
            FA[mf * 2 + kk], FB[nf * 2 + kk], acc[(MH) * 4 + mf][(NH) * 2 + nf], 0, 0, 0); \
  __builtin_amdgcn_s_setprio(0);

__global__ __launch_bounds__(512, 2) void gemm256(const ushort* __restrict__ Abm,
                                                  const ushort* __restrict__ Btm,
                                                  float* __restrict__ C) {
  __shared__ ushort LDS[65536];   // 128 KiB: A dbuf 2x32KB | B dbuf 2x32KB
  const int t = threadIdx.x, w = t >> 6, l = t & 63;
  const int lr = l & 15, lh = l >> 4;
  const int wm = w >> 2, wn = w & 3;   // 2M x 4N wave grid, per-wave out 128x64

  // T1: bijective XCD swizzle (256 blocks, 8 XCDs, 32 blocks/XCD)
  int orig = blockIdx.x;
  int wg = (orig & 7) * 32 + (orig >> 3);
  int bm = wg >> 4, bn = wg & 15;
  const size_t m0 = (size_t)bm * 256, n0 = (size_t)bn * 256;
  const ushort* Agl = Abm + m0 * N_NODES;
  const ushort* Bgl = Btm + n0 * N_NODES;

  // staging bases (h/j offsets are compile-time immediates in STAGE_*)
  const int laB = ((w < 4) ? 0 : 16384) + ((2 * w) & 7) * 1024 + l * 16;   // bytes
  const int raB = laB >> 7, saB = (laB >> 4) & 7;
  const long goA = (long)raB * N_NODES + (long)((saB ^ (raB & 7)) * 8);    // elements
  const int lbB = (w >> 1) * 8192 + (w & 1) * 2048 + l * 16;               // bytes
  const int rbB = lbB >> 7, sbB = (lbB >> 4) & 7;
  const long goB = (long)rbB * N_NODES + (long)((sbB ^ (rbB & 7)) * 8);

  // ds_read fragment bases (element units); mf/nf step = 1024 elements
  const int aR0 = wm * 128 + lr;
  const int aE0 = aR0 * 64 + ((lh ^ (lr & 7)) * 8);
  const int aE1 = aR0 * 64 + (((lh + 4) ^ (lr & 7)) * 8);
  const int bR0 = wn * 64 + lr;
  const int bE0 = bR0 * 64 + ((lh ^ (lr & 7)) * 8);
  const int bE1 = bR0 * 64 + (((lh + 4) ^ (lr & 7)) * 8);

  f32x4 acc[8][4];
  #pragma unroll
  for (int i = 0; i < 8; ++i)
    #pragma unroll
    for (int j = 0; j < 4; ++j) acc[i][j] = (f32x4){0.f, 0.f, 0.f, 0.f};

  bf16x8 fa0[8], fa1[8], fb0[4], fb1[4];

  // prologue: stage tile 0 (A0,B0,A1,B1), drain, barrier
  STAGE_A(0, 0, 0) STAGE_B(0, 0, 0) STAGE_A(1, 0, 0) STAGE_B(1, 0, 0)
  VM0
  SBAR

  for (int kt = 0; kt < NT - 1; ++kt) {
    int p = kt & 1, pn = p ^ 1;
    const ushort* PA = LDS + p * 16384;
    const ushort* PB = LDS + 32768 + p * 16384;
    // P1: reads fa0,fb0 issued pre-barrier (data visible since kt-1 P3/P4)
    LDA8(fa0, PA, 0) LDB4(fb0, PB, 0)
    STAGE_A(0, kt + 1, pn) VM4 SBAR
    LGKM0 QUAD(0, 0, fa0, fb0)
    // P2: read fa1 (A1(kt) retired @ P1's VM4, visible after P1's SBAR)
    LDA8(fa1, PA, 1)
    STAGE_B(0, kt + 1, pn) VM4 SBAR
    LGKM0 QUAD(1, 0, fa1, fb0)
    // P3: read fb1 (B1(kt) retired @ P2's VM4)
    LDB4(fb1, PB, 1)
    STAGE_A(1, kt + 1, pn) VM4 SBAR
    LGKM0 QUAD(0, 1, fa0, fb1)
    // P4: no reads; all fragments in regs
    STAGE_B(1, kt + 1, pn) VM4 SBAR
    QUAD(1, 1, fa1, fb1)
  }
  { // last tile (kt = 127, buf 1): no staging, incremental drain
    const ushort* PA = LDS + 16384;
    const ushort* PB = LDS + 32768 + 16384;
    LDA8(fa0, PA, 0) LDB4(fb0, PB, 0)
    VM2 SBAR
    LGKM0 QUAD(0, 0, fa0, fb0)
    LDA8(fa1, PA, 1)
    VM0 SBAR
    LGKM0 QUAD(1, 0, fa1, fb0)
    LDB4(fb1, PB, 1)
    SBAR
    LGKM0 QUAD(0, 1, fa0, fb1)
    QUAD(1, 1, fa1, fb1)
  }

  // epilogue: C/D layout col=lane&15, row=(lane>>4)*4+r  [m89-verified]
  #pragma unroll
  for (int mf = 0; mf < 8; ++mf) {
    #pragma unroll
    for (int nf = 0; nf < 4; ++nf) {
      float* cp = C + (m0 + wm * 128 + mf * 16 + lh * 4) * K_SEL + n0 + wn * 64 + nf * 16 + lr;
      #pragma unroll
      for (int r = 0; r < 4; ++r) cp[(size_t)r * K_SEL] = acc[mf][nf][r];
    }
  }
}

// 7. X_pooled[m,f] = X[idx[m],f] * tanh(y[idx[m]])
__global__ void xpool(const float* __restrict__ X, const float* __restrict__ y,
                      const int* __restrict__ idx, float* __restrict__ out) {
  int m = blockIdx.x;
  int i = idx[m];
  float th = tanhf(y[i]);
  out[(size_t)m * F_DIM + threadIdx.x] = X[(size_t)i * F_DIM + threadIdx.x] * th;
}

extern "C" void kernel_launch(void* const* d_in, const int* in_sizes, int n_in,
                              void* d_out, int out_size, void* d_ws, size_t ws_size,
                              hipStream_t stream) {
  const float* X    = (const float*)d_in[0];
  const float* A    = (const float*)d_in[1];
  const float* kern = (const float*)d_in[2];
  float* out = (float*)d_out;
  float* Xp = out;                                 // 4096*256
  float* Ap = out + (size_t)K_SEL * F_DIM;         // 4096*4096

  char* ws = (char*)d_ws;
  float* Xk      = (float*)(ws);                   // 8192 f32
  float* yv      = (float*)(ws + 32 * 1024);       // 8192 f32
  int*   idx     = (int*)  (ws + 64 * 1024);       // 4096 i32
  int*   rank    = (int*)  (ws + 96 * 1024);       // 8193 i32
  int*   sel     = (int*)  (ws + 160 * 1024);      // 8192 i32
  int*   partial = (int*)  (ws + 192 * 1024);      // 8*8192 i32 = 256 KB
  ushort* Ab = (ushort*)(ws + 512 * 1024);                                   // 64 MB
  ushort* Bt = (ushort*)(ws + 512 * 1024 + (size_t)K_SEL * N_NODES * 2);     // 64 MB

  xk_kernel  <<<N_NODES, 256, 0, stream>>>(X, kern, Xk);
  gemv_kernel<<<N_NODES, 256, 0, stream>>>(A, Xk, yv);
  rank2d     <<<dim3(32, 8), 256, 0, stream>>>(yv, partial);
  scan_kernel<<<1, 1024, 0, stream>>>(partial, sel, idx, rank);
  gatherAB   <<<dim3(N_NODES / GC, N_NODES / GR), 256, 0, stream>>>(A, sel, rank, Ab, Bt);
  gemm256    <<<256, 512, 0, stream>>>(Ab, Bt, Ap);
  xpool      <<<K_SEL, 256, 0, stream>>>(X, yv, idx, Xp);
}

// Round 6
// 272.401 us; speedup vs baseline: 2.9455x; 1.3957x over previous
//
#include <hip/hip_runtime.h>
#include <hip/hip_bf16.h>
#include <stdint.h>

#define N_NODES 8192
#define F_DIM 256
#define K_SEL 4096

typedef unsigned char u8;
typedef __attribute__((ext_vector_type(4))) int i32x4;
typedef __attribute__((ext_vector_type(8))) int i32x8;
typedef __attribute__((ext_vector_type(16))) float f32x16;

// 1. Xk[i] = sum_f X[i,f]*kernel[f]   (fp64 accumulate)
__global__ void xk_kernel(const float* __restrict__ X, const float* __restrict__ kern,
                          float* __restrict__ Xk) {
  __shared__ double red[256];
  int row = blockIdx.x, t = threadIdx.x;
  double p = (double)X[(size_t)row * F_DIM + t] * (double)kern[t];
  red[t] = p; __syncthreads();
  for (int off = 128; off > 0; off >>= 1) {
    if (t < off) red[t] += red[t + off];
    __syncthreads();
  }
  if (t == 0) Xk[row] = (float)red[0];
}

// 2. y[i] = sum_j A[i,j]*Xk[j]   (fp64 accumulate, float4 loads)
__global__ void gemv_kernel(const float* __restrict__ A, const float* __restrict__ Xk,
                            float* __restrict__ y) {
  __shared__ double red[256];
  int row = blockIdx.x, t = threadIdx.x;
  const float4* ar = (const float4*)(A + (size_t)row * N_NODES);
  const float4* xk = (const float4*)Xk;
  double s = 0.0;
  #pragma unroll 4
  for (int j = t; j < N_NODES / 4; j += 256) {
    float4 a = ar[j], x = xk[j];
    s += (double)a.x * x.x + (double)a.y * x.y + (double)a.z * x.z + (double)a.w * x.w;
  }
  red[t] = s; __syncthreads();
  for (int off = 128; off > 0; off >>= 1) {
    if (t < off) red[t] += red[t + off];
    __syncthreads();
  }
  if (t == 0) y[row] = (float)red[0];
}

// 3. partial ranks over j-chunks of 1024; 256 blocks -> full-chip
__global__ void rank2d(const float* __restrict__ y, int* __restrict__ partial) {
  __shared__ float sc[1024];
  int i = blockIdx.x * 256 + threadIdx.x;
  float si = y[i];
  int j0 = blockIdx.y * 1024;
  for (int c = threadIdx.x; c < 1024; c += 256) sc[c] = y[j0 + c];
  __syncthreads();
  int cnt = 0;
  #pragma unroll 8
  for (int jj = 0; jj < 1024; ++jj) {
    float sj = sc[jj];
    int j = j0 + jj;
    cnt += (sj > si) || (sj == si && j < i);
  }
  partial[blockIdx.y * N_NODES + i] = cnt;
}

// 4. sum partials -> sel; ordered compaction -> idx ascending + prefix rank[0..N]
__global__ void scan_kernel(const int* __restrict__ partial, int* __restrict__ sel,
                            int* __restrict__ idx, int* __restrict__ rank) {
  __shared__ int ps[1024];
  int t = threadIdx.x;
  int base = t * 8;
  int loc[8]; int s = 0;
  #pragma unroll
  for (int k = 0; k < 8; k++) {
    int cnt = 0;
    #pragma unroll
    for (int b = 0; b < 8; b++) cnt += partial[b * N_NODES + base + k];
    loc[k] = (cnt < K_SEL) ? 1 : 0;
    s += loc[k];
  }
  ps[t] = s; __syncthreads();
  for (int off = 1; off < 1024; off <<= 1) {
    int v = (t >= off) ? ps[t - off] : 0;
    __syncthreads();
    ps[t] += v;
    __syncthreads();
  }
  int pos = (t > 0) ? ps[t - 1] : 0;
  #pragma unroll
  for (int k = 0; k < 8; k++) {
    sel[base + k] = loc[k];
    rank[base + k] = pos;
    if (loc[k]) { idx[pos] = base + k; pos++; }
  }
  if (t == 1023) rank[N_NODES] = ps[1023];
}

// 5. fused gather -> fp8 e4m3 (scale 1.0): Ab8[rank[r]][k]=fp8(A[r][k]),
//    Bt8[rank[c]][k]=fp8(A[k][c]) transposed in LDS. 34 KB LDS -> 4 blocks/CU.
#define GR 128
#define GC 256
#define GS 260
__global__ __launch_bounds__(256) void gatherAB(const float* __restrict__ A,
                                                const int* __restrict__ sel,
                                                const int* __restrict__ rank,
                                                u8* __restrict__ Ab8,
                                                u8* __restrict__ Bt8) {
  __shared__ u8 tile[GR][GS];
  __shared__ short rlist[GR];
  __shared__ short clist[GC];
  int t = threadIdx.x, w = t >> 6, l = t & 63;
  int r0 = blockIdx.y * GR, c0 = blockIdx.x * GC;
  // load+convert: 16 lanes x 16B = 256B contiguous per row-segment
  #pragma unroll
  for (int p = 0; p < 8; ++p) {
    int r = p * 16 + (t >> 4);
    const float4* src = (const float4*)(A + (size_t)(r0 + r) * N_NODES + c0);
    #pragma unroll
    for (int j = 0; j < 4; ++j) {
      int c4 = (t & 15) + j * 16;
      float4 v = src[c4];
      int pk = __builtin_amdgcn_cvt_pk_fp8_f32(v.x, v.y, 0, false);
      pk = __builtin_amdgcn_cvt_pk_fp8_f32(v.z, v.w, pk, true);
      *(int*)&tile[r][c4 * 4] = pk;
    }
  }
  int rbase = rank[r0], cbase = rank[c0];
  if (t < GR && sel[r0 + t]) rlist[rank[r0 + t] - rbase] = (short)t;
  if (sel[c0 + t]) clist[rank[c0 + t] - cbase] = (short)t;
  int nR = rank[r0 + GR] - rbase;
  int nC = rank[c0 + GC] - cbase;
  __syncthreads();
  // Ab rows: 64 lanes x 4B = 256B coalesced per selected row
  for (int j = w; j < nR; j += 4) {
    int r = rlist[j];
    *(unsigned int*)(Ab8 + (size_t)(rbase + j) * N_NODES + c0 + l * 4) =
        *(const unsigned int*)&tile[r][l * 4];
  }
  // Bt cols: lane l packs rows {2l,2l+1} -> 128B per selected col
  for (int j = w; j < nC; j += 4) {
    int c = clist[j];
    unsigned short v = (unsigned short)(tile[2 * l][c] | (tile[2 * l + 1][c] << 8));
    *(unsigned short*)(Bt8 + (size_t)(cbase + j) * N_NODES + r0 + 2 * l) = v;
  }
}

// ============================================================================
// 6. C = Ab8(MxK) * Bt8(NxK)^T in MX-fp8 (scale=1.0): 256x256 tile, BK=128,
//    NT=64 K-tiles, 8 waves (2Mx4N), mfma_scale_f32_32x32x64_f8f6f4 (e4m3).
//    Same verified skeleton as bf16 version: 4 phases/K-tile, frag reuse
//    (P1: A0+B0, P2: A1, P3: B1, P4: none), phase-top reads, 1 barrier/phase,
//    VM4 ledger (A0(kt)@kt-1P3, B0@kt-1P4, A1@ktP1, B1@ktP2), T2 XOR swizzle,
//    T5 setprio, T1 XCD swizzle. LDS 128 KiB: A dbuf 2x32KB | B dbuf 2x32KB.
//    A-half h = rows with bit6==h (128 rows x 128B = 16KB = 2 GLL sweeps);
//    B-half h = rows with bit5==h.
// ============================================================================
#define NT2 64   // 8192 / 128

#define GLL(g, s) __builtin_amdgcn_global_load_lds( \
    (const __attribute__((address_space(1))) void*)(g), \
    (__attribute__((address_space(3))) void*)(s), 16, 0, 0)

#define STAGE_A(H, KTN, DSTP) \
  GLL(Agl + aSrc + (H) * 524288 + (size_t)(KTN) * 128,           LDS + (DSTP) * 32768 + (H) * 16384 + t * 16); \
  GLL(Agl + aSrc + (H) * 524288 + 1048576 + (size_t)(KTN) * 128, LDS + (DSTP) * 32768 + (H) * 16384 + 8192 + t * 16);

#define STAGE_B(H, KTN, DSTP) \
  GLL(Bgl + bSrc + (H) * 262144 + (size_t)(KTN) * 128,           LDS + 65536 + (DSTP) * 32768 + (H) * 16384 + t * 16); \
  GLL(Bgl + bSrc + (H) * 262144 + 1048576 + (size_t)(KTN) * 128, LDS + 65536 + (DSTP) * 32768 + (H) * 16384 + 8192 + t * 16);

#define VM4 asm volatile("s_waitcnt vmcnt(4)" ::: "memory");
#define VM2 asm volatile("s_waitcnt vmcnt(2)" ::: "memory");
#define VM0 asm volatile("s_waitcnt vmcnt(0)" ::: "memory");
#define SBAR asm volatile("s_barrier" ::: "memory");
#define LGKM0 asm volatile("s_waitcnt lgkmcnt(0)" ::: "memory"); __builtin_amdgcn_sched_barrier(0);

// load one A-half: 2 m-frags x 2 k-steps x 32B (8 x ds_read_b128)
#define LDA8F(DST, PAB, MH) { \
  const u8* b_ = (PAB) + (MH) * 16384 + pA; \
  _Pragma("unroll") \
  for (int q = 0; q < 2; ++q) { \
    i32x4 x0 = *(const i32x4*)(b_ + q * 4096 + o00); \
    i32x4 x1 = *(const i32x4*)(b_ + q * 4096 + o01); \
    i32x4 y0 = *(const i32x4*)(b_ + q * 4096 + o10); \
    i32x4 y1 = *(const i32x4*)(b_ + q * 4096 + o11); \
    DST[q * 2 + 0] = __builtin_shufflevector(x0, x1, 0, 1, 2, 3, 4, 5, 6, 7); \
    DST[q * 2 + 1] = __builtin_shufflevector(y0, y1, 0, 1, 2, 3, 4, 5, 6, 7); } }

// load one B-half: 1 n-frag x 2 k-steps x 32B (4 x ds_read_b128)
#define LDB4F(DST, PBB, NH) { \
  const u8* b_ = (PBB) + (NH) * 16384 + pB; \
  i32x4 x0 = *(const i32x4*)(b_ + o00); \
  i32x4 x1 = *(const i32x4*)(b_ + o01); \
  i32x4 y0 = *(const i32x4*)(b_ + o10); \
  i32x4 y1 = *(const i32x4*)(b_ + o11); \
  DST[0] = __builtin_shufflevector(x0, x1, 0, 1, 2, 3, 4, 5, 6, 7); \
  DST[1] = __builtin_shufflevector(y0, y1, 0, 1, 2, 3, 4, 5, 6, 7); }

#define QUADF(MH, NH, FA, FB) \
  __builtin_amdgcn_s_setprio(1); \
  _Pragma("unroll") \
  for (int ks = 0; ks < 2; ++ks) \
    _Pragma("unroll") \
    for (int q = 0; q < 2; ++q) \
      acc[(MH) * 2 + q][NH] = __builtin_amdgcn_mfma_scale_f32_32x32x64_f8f6f4( \
          FA[q * 2 + ks], FB[ks], acc[(MH) * 2 + q][NH], 0, 0, \
          0, 0x7F7F7F7F, 0, 0x7F7F7F7F); \
  __builtin_amdgcn_s_setprio(0);

__global__ __launch_bounds__(512, 2) void gemm256(const u8* __restrict__ Abm,
                                                  const u8* __restrict__ Btm,
                                                  float* __restrict__ C) {
  __shared__ u8 LDS[131072];
  const int t = threadIdx.x, w = t >> 6, l = t & 63;
  const int l31 = l & 31, g = l >> 5;
  const int wm = w >> 2, wn = w & 3;   // 2M x 4N wave grid, per-wave out 128x64

  // T1: bijective XCD swizzle (256 blocks, 8 XCDs, 32 blocks/XCD)
  int orig = blockIdx.x;
  int wg = (orig & 7) * 32 + (orig >> 3);
  int bm = wg >> 4, bn = wg & 15;
  const size_t m0 = (size_t)bm * 256, n0 = (size_t)bn * 256;
  const u8* Agl = Abm + m0 * N_NODES;
  const u8* Bgl = Btm + n0 * N_NODES;

  // staging source bases (inverse-swizzled); dest is linear t*16
  const int trow = t >> 3;                              // 0..63
  const int csw = ((t & 7) ^ (trow & 7)) * 16;          // swizzled 16B chunk
  const size_t aSrc = (size_t)trow * N_NODES + csw;     // + h*64rows + s*128rows
  const size_t bSrc = (size_t)((t >> 8) * 64 + (trow & 31)) * N_NODES + csw;

  // fragment ds_read bases (bytes): row p*128 + swizzled slot
  const int pA = (wm * 64 + l31) * 128;
  const int pB = (wn * 32 + l31) * 128;
  const int k7 = l31 & 7;
  const int o00 = ((g * 2 + 0) ^ k7) * 16;   // ks=0, chunk 0
  const int o01 = ((g * 2 + 1) ^ k7) * 16;   // ks=0, chunk 1
  const int o10 = ((g * 2 + 4) ^ k7) * 16;   // ks=1, chunk 0
  const int o11 = ((g * 2 + 5) ^ k7) * 16;   // ks=1, chunk 1

  f32x16 acc[4][2];
  #pragma unroll
  for (int i = 0; i < 4; ++i)
    #pragma unroll
    for (int j = 0; j < 2; ++j)
      #pragma unroll
      for (int r = 0; r < 16; ++r) acc[i][j][r] = 0.f;

  i32x8 fa0[4], fa1[4], fb0[2], fb1[2];

  // prologue: stage tile 0 (A0,B0,A1,B1), drain, barrier
  STAGE_A(0, 0, 0) STAGE_B(0, 0, 0) STAGE_A(1, 0, 0) STAGE_B(1, 0, 0)
  VM0
  SBAR

  for (int kt = 0; kt < NT2 - 1; ++kt) {
    int p = kt & 1, pn = p ^ 1;
    const u8* PA = LDS + p * 32768;
    const u8* PB = LDS + 65536 + p * 32768;
    // P1: reads fa0,fb0 (visible since kt-1 P3/P4)
    LDA8F(fa0, PA, 0) LDB4F(fb0, PB, 0)
    STAGE_A(0, kt + 1, pn) VM4 SBAR
    LGKM0 QUADF(0, 0, fa0, fb0)
    // P2: read fa1 (A1(kt) retired @ P1's VM4)
    LDA8F(fa1, PA, 1)
    STAGE_B(0, kt + 1, pn) VM4 SBAR
    LGKM0 QUADF(1, 0, fa1, fb0)
    // P3: read fb1 (B1(kt) retired @ P2's VM4)
    LDB4F(fb1, PB, 1)
    STAGE_A(1, kt + 1, pn) VM4 SBAR
    LGKM0 QUADF(0, 1, fa0, fb1)
    // P4: all fragments in regs
    STAGE_B(1, kt + 1, pn) VM4 SBAR
    QUADF(1, 1, fa1, fb1)
  }
  { // last tile (kt = 63, buf 1): no staging, incremental drain
    const u8* PA = LDS + 32768;
    const u8* PB = LDS + 65536 + 32768;
    LDA8F(fa0, PA, 0) LDB4F(fb0, PB, 0)
    VM2 SBAR
    LGKM0 QUADF(0, 0, fa0, fb0)
    LDA8F(fa1, PA, 1)
    VM0 SBAR
    LGKM0 QUADF(1, 0, fa1, fb0)
    LDB4F(fb1, PB, 1)
    SBAR
    LGKM0 QUADF(0, 1, fa0, fb1)
    QUADF(1, 1, fa1, fb1)
  }

  // epilogue: 32x32 C/D layout col=lane&31, row=(reg&3)+8*(reg>>2)+4*(lane>>5)
  #pragma unroll
  for (int mf = 0; mf < 4; ++mf) {
    #pragma unroll
    for (int nf = 0; nf < 2; ++nf) {
      #pragma unroll
      for (int r = 0; r < 16; ++r) {
        int row = (r & 3) + 8 * (r >> 2) + 4 * g;
        C[(m0 + wm * 128 + mf * 32 + row) * K_SEL + n0 + wn * 64 + nf * 32 + l31] =
            acc[mf][nf][r];
      }
    }
  }
}

// 7. X_pooled[m,f] = X[idx[m],f] * tanh(y[idx[m]])
__global__ void xpool(const float* __restrict__ X, const float* __restrict__ y,
                      const int* __restrict__ idx, float* __restrict__ out) {
  int m = blockIdx.x;
  int i = idx[m];
  float th = tanhf(y[i]);
  out[(size_t)m * F_DIM + threadIdx.x] = X[(size_t)i * F_DIM + threadIdx.x] * th;
}

extern "C" void kernel_launch(void* const* d_in, const int* in_sizes, int n_in,
                              void* d_out, int out_size, void* d_ws, size_t ws_size,
                              hipStream_t stream) {
  const float* X    = (const float*)d_in[0];
  const float* A    = (const float*)d_in[1];
  const float* kern = (const float*)d_in[2];
  float* out = (float*)d_out;
  float* Xp = out;                                 // 4096*256
  float* Ap = out + (size_t)K_SEL * F_DIM;         // 4096*4096

  char* ws = (char*)d_ws;
  float* Xk      = (float*)(ws);                   // 8192 f32
  float* yv      = (float*)(ws + 32 * 1024);       // 8192 f32
  int*   idx     = (int*)  (ws + 64 * 1024);       // 4096 i32
  int*   rank    = (int*)  (ws + 96 * 1024);       // 8193 i32
  int*   sel     = (int*)  (ws + 160 * 1024);      // 8192 i32
  int*   partial = (int*)  (ws + 192 * 1024);      // 8*8192 i32 = 256 KB
  u8* Ab8 = (u8*)(ws + 512 * 1024);                                  // 32 MB
  u8* Bt8 = (u8*)(ws + 512 * 1024 + (size_t)K_SEL * N_NODES);        // 32 MB

  xk_kernel  <<<N_NODES, 256, 0, stream>>>(X, kern, Xk);
  gemv_kernel<<<N_NODES, 256, 0, stream>>>(A, Xk, yv);
  rank2d     <<<dim3(32, 8), 256, 0, stream>>>(yv, partial);
  scan_kernel<<<1, 1024, 0, stream>>>(partial, sel, idx, rank);
  gatherAB   <<<dim3(N_NODES / GC, N_NODES / GR), 256, 0, stream>>>(A, sel, rank, Ab8, Bt8);
  gemm256    <<<256, 512, 0, stream>>>(Ab8, Bt8, Ap);
  xpool      <<<K_SEL, 256, 0, stream>>>(X, yv, idx, Xp);
}

// Round 7
// 238.158 us; speedup vs baseline: 3.3690x; 1.1438x over previous
//
#include <hip/hip_runtime.h>
#include <hip/hip_bf16.h>
#include <stdint.h>

#define N_NODES 8192
#define F_DIM 256
#define K_SEL 4096

typedef unsigned char u8;
typedef __attribute__((ext_vector_type(4))) int i32x4;
typedef __attribute__((ext_vector_type(8))) int i32x8;
typedef __attribute__((ext_vector_type(16))) float f32x16;

// 1. Xk[i] = sum_f X[i,f]*kernel[f]   (fp64 accumulate)
__global__ void xk_kernel(const float* __restrict__ X, const float* __restrict__ kern,
                          float* __restrict__ Xk) {
  __shared__ double red[256];
  int row = blockIdx.x, t = threadIdx.x;
  double p = (double)X[(size_t)row * F_DIM + t] * (double)kern[t];
  red[t] = p; __syncthreads();
  for (int off = 128; off > 0; off >>= 1) {
    if (t < off) red[t] += red[t + off];
    __syncthreads();
  }
  if (t == 0) Xk[row] = (float)red[0];
}

// 2. fused prep: ONE pass over A emits Af8 (row-major fp8), At8 (transposed
//    fp8), and per-chunk fp64 gemv partials ypart[chunk][row] (deterministic).
#define PR 128
#define PC 256
__global__ __launch_bounds__(256) void prep8(const float* __restrict__ A,
                                             const float* __restrict__ Xk,
                                             u8* __restrict__ Af8,
                                             u8* __restrict__ At8,
                                             double* __restrict__ ypart) {
  __shared__ u8 tile[PR][PC + 4];
  __shared__ float sXk[PC];
  int t = threadIdx.x, w = t >> 6, l = t & 63;
  int c0 = blockIdx.x * PC, r0 = blockIdx.y * PR;
  if (t < PC / 4) *(float4*)&sXk[t * 4] = *(const float4*)&Xk[c0 + t * 4];
  __syncthreads();
  #pragma unroll
  for (int p = 0; p < 8; ++p) {
    int r = p * 16 + (t >> 4);
    const float4* src = (const float4*)(A + (size_t)(r0 + r) * N_NODES + c0);
    double d = 0.0;
    #pragma unroll
    for (int j = 0; j < 4; ++j) {
      int c4 = (t & 15) + j * 16;
      float4 v = src[c4];
      float4 x = *(const float4*)&sXk[c4 * 4];
      d += (double)v.x * x.x + (double)v.y * x.y + (double)v.z * x.z + (double)v.w * x.w;
      int pk = __builtin_amdgcn_cvt_pk_fp8_f32(v.x, v.y, 0, false);
      pk = __builtin_amdgcn_cvt_pk_fp8_f32(v.z, v.w, pk, true);
      *(int*)&tile[r][c4 * 4] = pk;
    }
    d += __shfl_xor(d, 1); d += __shfl_xor(d, 2);
    d += __shfl_xor(d, 4); d += __shfl_xor(d, 8);
    if ((t & 15) == 0) ypart[(size_t)blockIdx.x * N_NODES + r0 + r] = d;
  }
  __syncthreads();
  // Af8 rows: 64 lanes x 4B = 256B coalesced per row
  for (int j = w; j < PR; j += 4)
    *(unsigned int*)(Af8 + (size_t)(r0 + j) * N_NODES + c0 + l * 4) =
        *(const unsigned int*)&tile[j][l * 4];
  // At8 cols: lane l packs rows {2l,2l+1} -> 128B contiguous per col
  for (int j = w; j < PC; j += 4) {
    unsigned short v = (unsigned short)(tile[2 * l][j] | (tile[2 * l + 1][j] << 8));
    *(unsigned short*)(At8 + (size_t)(c0 + j) * N_NODES + r0 + 2 * l) = v;
  }
}

// 3. y[i] = sum over 32 col-chunk partials (fp64, fixed order -> deterministic)
__global__ void yreduce(const double* __restrict__ ypart, float* __restrict__ y) {
  int i = blockIdx.x * 256 + threadIdx.x;
  double s = 0.0;
  #pragma unroll
  for (int b = 0; b < 32; ++b) s += ypart[(size_t)b * N_NODES + i];
  y[i] = (float)s;
}

// 4. partial ranks over j-chunks of 1024; 256 blocks -> full-chip
__global__ void rank2d(const float* __restrict__ y, int* __restrict__ partial) {
  __shared__ float sc[1024];
  int i = blockIdx.x * 256 + threadIdx.x;
  float si = y[i];
  int j0 = blockIdx.y * 1024;
  for (int c = threadIdx.x; c < 1024; c += 256) sc[c] = y[j0 + c];
  __syncthreads();
  int cnt = 0;
  #pragma unroll 8
  for (int jj = 0; jj < 1024; ++jj) {
    float sj = sc[jj];
    int j = j0 + jj;
    cnt += (sj > si) || (sj == si && j < i);
  }
  partial[blockIdx.y * N_NODES + i] = cnt;
}

// 5. sum partials; ordered compaction -> idx[0..K-1] ascending
__global__ void scan_kernel(const int* __restrict__ partial, int* __restrict__ idx) {
  __shared__ int ps[1024];
  int t = threadIdx.x;
  int base = t * 8;
  int loc[8]; int s = 0;
  #pragma unroll
  for (int k = 0; k < 8; k++) {
    int cnt = 0;
    #pragma unroll
    for (int b = 0; b < 8; b++) cnt += partial[b * N_NODES + base + k];
    loc[k] = (cnt < K_SEL) ? 1 : 0;
    s += loc[k];
  }
  ps[t] = s; __syncthreads();
  for (int off = 1; off < 1024; off <<= 1) {
    int v = (t >= off) ? ps[t - off] : 0;
    __syncthreads();
    ps[t] += v;
    __syncthreads();
  }
  int pos = (t > 0) ? ps[t - 1] : 0;
  #pragma unroll
  for (int k = 0; k < 8; k++) {
    if (loc[k]) { idx[pos] = base + k; pos++; }
  }
}

// ============================================================================
// 6. C = A[idx,:][:,idx]^2-style product via MX-fp8 (scale=1.0):
//    C[m][n] = sum_k Af8[idx[m]][k] * At8[idx[n]][k].  256x256 tile, BK=128,
//    NT2=64 K-tiles, 8 waves (2Mx4N), mfma_scale_f32_32x32x64_f8f6f4 (e4m3).
//    INDEXED STAGING: global_load_lds source row = idx[...]<<13 (N=2^13), so
//    no packed intermediate is needed. Same verified skeleton: 4 phases/K-tile,
//    frag reuse (P1: A0+B0, P2: A1, P3: B1, P4: none), phase-top reads, one
//    barrier/phase, VM4 ledger, T2 XOR swizzle, T5 setprio, T1 XCD swizzle.
// ============================================================================
#define NT2 64   // 8192 / 128

#define GLL(g, s) __builtin_amdgcn_global_load_lds( \
    (const __attribute__((address_space(1))) void*)(g), \
    (__attribute__((address_space(3))) void*)(s), 16, 0, 0)

#define STAGE_A(H, KTN, DSTP) \
  GLL(Af + aOf##H##0 + (size_t)(KTN) * 128, LDS + (DSTP) * 32768 + (H) * 16384 + t * 16); \
  GLL(Af + aOf##H##1 + (size_t)(KTN) * 128, LDS + (DSTP) * 32768 + (H) * 16384 + 8192 + t * 16);

#define STAGE_B(H, KTN, DSTP) \
  GLL(At + bOf##H##0 + (size_t)(KTN) * 128, LDS + 65536 + (DSTP) * 32768 + (H) * 16384 + t * 16); \
  GLL(At + bOf##H##1 + (size_t)(KTN) * 128, LDS + 65536 + (DSTP) * 32768 + (H) * 16384 + 8192 + t * 16);

#define VM4 asm volatile("s_waitcnt vmcnt(4)" ::: "memory");
#define VM2 asm volatile("s_waitcnt vmcnt(2)" ::: "memory");
#define VM0 asm volatile("s_waitcnt vmcnt(0)" ::: "memory");
#define SBAR asm volatile("s_barrier" ::: "memory");
#define LGKM0 asm volatile("s_waitcnt lgkmcnt(0)" ::: "memory"); __builtin_amdgcn_sched_barrier(0);

// load one A-half: 2 m-frags x 2 k-steps x 32B (8 x ds_read_b128)
#define LDA8F(DST, PAB, MH) { \
  const u8* b_ = (PAB) + (MH) * 16384 + pA; \
  _Pragma("unroll") \
  for (int q = 0; q < 2; ++q) { \
    i32x4 x0 = *(const i32x4*)(b_ + q * 4096 + o00); \
    i32x4 x1 = *(const i32x4*)(b_ + q * 4096 + o01); \
    i32x4 y0 = *(const i32x4*)(b_ + q * 4096 + o10); \
    i32x4 y1 = *(const i32x4*)(b_ + q * 4096 + o11); \
    DST[q * 2 + 0] = __builtin_shufflevector(x0, x1, 0, 1, 2, 3, 4, 5, 6, 7); \
    DST[q * 2 + 1] = __builtin_shufflevector(y0, y1, 0, 1, 2, 3, 4, 5, 6, 7); } }

// load one B-half: 1 n-frag x 2 k-steps x 32B (4 x ds_read_b128)
#define LDB4F(DST, PBB, NH) { \
  const u8* b_ = (PBB) + (NH) * 16384 + pB; \
  i32x4 x0 = *(const i32x4*)(b_ + o00); \
  i32x4 x1 = *(const i32x4*)(b_ + o01); \
  i32x4 y0 = *(const i32x4*)(b_ + o10); \
  i32x4 y1 = *(const i32x4*)(b_ + o11); \
  DST[0] = __builtin_shufflevector(x0, x1, 0, 1, 2, 3, 4, 5, 6, 7); \
  DST[1] = __builtin_shufflevector(y0, y1, 0, 1, 2, 3, 4, 5, 6, 7); }

#define QUADF(MH, NH, FA, FB) \
  __builtin_amdgcn_s_setprio(1); \
  _Pragma("unroll") \
  for (int ks = 0; ks < 2; ++ks) \
    _Pragma("unroll") \
    for (int q = 0; q < 2; ++q) \
      acc[(MH) * 2 + q][NH] = __builtin_amdgcn_mfma_scale_f32_32x32x64_f8f6f4( \
          FA[q * 2 + ks], FB[ks], acc[(MH) * 2 + q][NH], 0, 0, \
          0, 0x7F7F7F7F, 0, 0x7F7F7F7F); \
  __builtin_amdgcn_s_setprio(0);

__global__ __launch_bounds__(512, 2) void gemm256(const u8* __restrict__ Af,
                                                  const u8* __restrict__ At,
                                                  const int* __restrict__ idxArr,
                                                  float* __restrict__ C) {
  __shared__ u8 LDS[131072];
  const int t = threadIdx.x, w = t >> 6, l = t & 63;
  const int l31 = l & 31, g = l >> 5;
  const int wm = w >> 2, wn = w & 3;   // 2M x 4N wave grid, per-wave out 128x64

  // T1: bijective XCD swizzle (256 blocks, 8 XCDs, 32 blocks/XCD)
  int orig = blockIdx.x;
  int wg = (orig & 7) * 32 + (orig >> 3);
  int bm = wg >> 4, bn = wg & 15;
  const int mi0 = bm * 256, ni0 = bn * 256;
  const size_t m0 = (size_t)mi0, n0 = (size_t)ni0;

  // indexed staging sources (inverse-swizzled chunk within the row)
  const int trow = t >> 3;                              // 0..63
  const int csw = ((t & 7) ^ (trow & 7)) * 16;          // swizzled 16B chunk
  const unsigned aOf00 = ((unsigned)idxArr[mi0 + trow] << 13) | csw;         // H0,s0
  const unsigned aOf01 = ((unsigned)idxArr[mi0 + trow + 128] << 13) | csw;   // H0,s1
  const unsigned aOf10 = ((unsigned)idxArr[mi0 + trow + 64] << 13) | csw;    // H1,s0
  const unsigned aOf11 = ((unsigned)idxArr[mi0 + trow + 192] << 13) | csw;   // H1,s1
  const int bRow = (t >> 8) * 64 + (trow & 31);
  const unsigned bOf00 = ((unsigned)idxArr[ni0 + bRow] << 13) | csw;         // H0,s0
  const unsigned bOf01 = ((unsigned)idxArr[ni0 + bRow + 128] << 13) | csw;   // H0,s1
  const unsigned bOf10 = ((unsigned)idxArr[ni0 + bRow + 32] << 13) | csw;    // H1,s0
  const unsigned bOf11 = ((unsigned)idxArr[ni0 + bRow + 160] << 13) | csw;   // H1,s1

  // fragment ds_read bases (bytes): row p*128 + swizzled slot
  const int pA = (wm * 64 + l31) * 128;
  const int pB = (wn * 32 + l31) * 128;
  const int k7 = l31 & 7;
  const int o00 = ((g * 2 + 0) ^ k7) * 16;   // ks=0, chunk 0
  const int o01 = ((g * 2 + 1) ^ k7) * 16;   // ks=0, chunk 1
  const int o10 = ((g * 2 + 4) ^ k7) * 16;   // ks=1, chunk 0
  const int o11 = ((g * 2 + 5) ^ k7) * 16;   // ks=1, chunk 1

  f32x16 acc[4][2];
  #pragma unroll
  for (int i = 0; i < 4; ++i)
    #pragma unroll
    for (int j = 0; j < 2; ++j)
      #pragma unroll
      for (int r = 0; r < 16; ++r) acc[i][j][r] = 0.f;

  i32x8 fa0[4], fa1[4], fb0[2], fb1[2];

  // prologue: stage tile 0 (A0,B0,A1,B1), drain, barrier
  STAGE_A(0, 0, 0) STAGE_B(0, 0, 0) STAGE_A(1, 0, 0) STAGE_B(1, 0, 0)
  VM0
  SBAR

  for (int kt = 0; kt < NT2 - 1; ++kt) {
    int p = kt & 1, pn = p ^ 1;
    const u8* PA = LDS + p * 32768;
    const u8* PB = LDS + 65536 + p * 32768;
    // P1: reads fa0,fb0 (visible since kt-1 P3/P4)
    LDA8F(fa0, PA, 0) LDB4F(fb0, PB, 0)
    STAGE_A(0, kt + 1, pn) VM4 SBAR
    LGKM0 QUADF(0, 0, fa0, fb0)
    // P2: read fa1 (A1(kt) retired @ P1's VM4)
    LDA8F(fa1, PA, 1)
    STAGE_B(0, kt + 1, pn) VM4 SBAR
    LGKM0 QUADF(1, 0, fa1, fb0)
    // P3: read fb1 (B1(kt) retired @ P2's VM4)
    LDB4F(fb1, PB, 1)
    STAGE_A(1, kt + 1, pn) VM4 SBAR
    LGKM0 QUADF(0, 1, fa0, fb1)
    // P4: all fragments in regs
    STAGE_B(1, kt + 1, pn) VM4 SBAR
    QUADF(1, 1, fa1, fb1)
  }
  { // last tile (kt = 63, buf 1): no staging, incremental drain
    const u8* PA = LDS + 32768;
    const u8* PB = LDS + 65536 + 32768;
    LDA8F(fa0, PA, 0) LDB4F(fb0, PB, 0)
    VM2 SBAR
    LGKM0 QUADF(0, 0, fa0, fb0)
    LDA8F(fa1, PA, 1)
    VM0 SBAR
    LGKM0 QUADF(1, 0, fa1, fb0)
    LDB4F(fb1, PB, 1)
    SBAR
    LGKM0 QUADF(0, 1, fa0, fb1)
    QUADF(1, 1, fa1, fb1)
  }

  // epilogue: 32x32 C/D layout col=lane&31, row=(reg&3)+8*(reg>>2)+4*(lane>>5)
  #pragma unroll
  for (int mf = 0; mf < 4; ++mf) {
    #pragma unroll
    for (int nf = 0; nf < 2; ++nf) {
      #pragma unroll
      for (int r = 0; r < 16; ++r) {
        int row = (r & 3) + 8 * (r >> 2) + 4 * g;
        C[(m0 + wm * 128 + mf * 32 + row) * K_SEL + n0 + wn * 64 + nf * 32 + l31] =
            acc[mf][nf][r];
      }
    }
  }
}

// 7. X_pooled[m,f] = X[idx[m],f] * tanh(y[idx[m]])
__global__ void xpool(const float* __restrict__ X, const float* __restrict__ y,
                      const int* __restrict__ idx, float* __restrict__ out) {
  int m = blockIdx.x;
  int i = idx[m];
  float th = tanhf(y[i]);
  out[(size_t)m * F_DIM + threadIdx.x] = X[(size_t)i * F_DIM + threadIdx.x] * th;
}

extern "C" void kernel_launch(void* const* d_in, const int* in_sizes, int n_in,
                              void* d_out, int out_size, void* d_ws, size_t ws_size,
                              hipStream_t stream) {
  const float* X    = (const float*)d_in[0];
  const float* A    = (const float*)d_in[1];
  const float* kern = (const float*)d_in[2];
  float* out = (float*)d_out;
  float* Xp = out;                                 // 4096*256
  float* Ap = out + (size_t)K_SEL * F_DIM;         // 4096*4096

  char* ws = (char*)d_ws;
  float*  Xk      = (float*) (ws);                 // 8192 f32
  float*  yv      = (float*) (ws + 32 * 1024);     // 8192 f32
  int*    idx     = (int*)   (ws + 64 * 1024);     // 4096 i32
  int*    partial = (int*)   (ws + 128 * 1024);    // 8*8192 i32 = 256 KB
  double* ypart   = (double*)(ws + 512 * 1024);    // 32*8192 f64 = 2 MB
  u8* Af8 = (u8*)(ws + 4 * 1024 * 1024);                               // 64 MB
  u8* At8 = (u8*)(ws + 4 * 1024 * 1024 + (size_t)N_NODES * N_NODES);   // 64 MB

  xk_kernel  <<<N_NODES, 256, 0, stream>>>(X, kern, Xk);
  prep8      <<<dim3(N_NODES / PC, N_NODES / PR), 256, 0, stream>>>(A, Xk, Af8, At8, ypart);
  yreduce    <<<N_NODES / 256, 256, 0, stream>>>(ypart, yv);
  rank2d     <<<dim3(32, 8), 256, 0, stream>>>(yv, partial);
  scan_kernel<<<1, 1024, 0, stream>>>(partial, idx);
  gemm256    <<<256, 512, 0, stream>>>(Af8, At8, idx, Ap);
  xpool      <<<K_SEL, 256, 0, stream>>>(X, yv, idx, Xp);
}